// Round 16
// baseline (4411.054 us; speedup 1.0000x reference)
//
#include <hip/hip_runtime.h>
#include <hip/hip_bf16.h>
#include <math.h>

// ---- problem constants ----
#define B_     64
#define NTOK   197
#define NPATCH 196
#define D768   768
#define NL     12
#define NH     12
#define MFF    3072
#define NCLS   1000
#define ROWS   (B_ * NTOK)      // 12608
#define PROWS  (B_ * NPATCH)    // 12544
#define ROWS_PAD 12800          // 50 * 256 (BM=256 for v8)

typedef unsigned short ushort;
typedef __bf16 bf16x8 __attribute__((ext_vector_type(8)));
typedef float  f32x4  __attribute__((ext_vector_type(4)));
typedef unsigned short u16x4 __attribute__((ext_vector_type(4)));
typedef unsigned short u16x2 __attribute__((ext_vector_type(2)));

__device__ __forceinline__ ushort f2b(float f) {
  __hip_bfloat16 h = __float2bfloat16(f);
  return *reinterpret_cast<ushort*>(&h);
}
__device__ __forceinline__ float b2f(ushort u) {
  unsigned int v = ((unsigned int)u) << 16;
  float f;
  __builtin_memcpy(&f, &v, 4);
  return f;
}

__device__ __forceinline__ void gload16(const ushort* g, ushort* lds) {
  __builtin_amdgcn_global_load_lds((const __attribute__((address_space(1))) void*)g,
                                   (__attribute__((address_space(3))) void*)lds, 16, 0, 0);
}

// tanh-form GELU via exp (max err ~1e-3, < bf16 quantization at those magnitudes)
__device__ __forceinline__ float gelu_f(float v) {
  float t = v * fmaf(0.0713548162726f, v * v, 1.5957691216f);
  return v / (1.0f + __expf(-t));
}

// ---------------- block-wide mean/rstd over 768 elems (256 threads) ----------------
__device__ __forceinline__ void block_mean_rstd(float s, float sq, float& mean, float& rstd) {
#pragma unroll
  for (int off = 32; off; off >>= 1) { s += __shfl_xor(s, off); sq += __shfl_xor(sq, off); }
  __shared__ float ss[4], ssq[4];
  int w = threadIdx.x >> 6;
  if ((threadIdx.x & 63) == 0) { ss[w] = s; ssq[w] = sq; }
  __syncthreads();
  s  = ss[0] + ss[1] + ss[2] + ss[3];
  sq = ssq[0] + ssq[1] + ssq[2] + ssq[3];
  mean = s * (1.0f / 768.0f);
  float var = sq * (1.0f / 768.0f) - mean * mean;
  rstd = rsqrtf(var + 1e-5f);
}

// ---------------- LN over rows of 768 (bf16 in, bf16 out), u16x4-vectorized ----------------
__global__ __launch_bounds__(256) void ln_rows_b(const ushort* __restrict__ in, long in_stride,
                                                 const float* __restrict__ g,
                                                 const float* __restrict__ bta,
                                                 ushort* __restrict__ out) {
  const ushort* xr = in + (size_t)blockIdx.x * in_stride;
  int t = threadIdx.x;
  float v0 = 0.f, v1 = 0.f, v2 = 0.f, v3 = 0.f;
  if (t < 192) {
    u16x4 xv = *(const u16x4*)(xr + t * 4);
    v0 = b2f(xv[0]); v1 = b2f(xv[1]); v2 = b2f(xv[2]); v3 = b2f(xv[3]);
  }
  float mean, rstd;
  block_mean_rstd(v0 + v1 + v2 + v3,
                  v0 * v0 + v1 * v1 + v2 * v2 + v3 * v3, mean, rstd);
  if (t < 192) {
    f32x4 gv = *(const f32x4*)(g + t * 4);
    f32x4 bv = *(const f32x4*)(bta + t * 4);
    u16x4 o = { f2b((v0 - mean) * rstd * gv[0] + bv[0]),
                f2b((v1 - mean) * rstd * gv[1] + bv[1]),
                f2b((v2 - mean) * rstd * gv[2] + bv[2]),
                f2b((v3 - mean) * rstd * gv[3] + bv[3]) };
    *(u16x4*)(out + (size_t)blockIdx.x * 768 + t * 4) = o;
  }
}

// ---------------- patch extraction + LN1 (bf16 out) ----------------
__global__ __launch_bounds__(256) void patch_ln1(const float* __restrict__ img,
                                                 const float* __restrict__ g,
                                                 const float* __restrict__ bta,
                                                 ushort* __restrict__ xp) {
  int pidx = blockIdx.x;                 // b*196 + ph*14 + pw
  int b = pidx / NPATCH, hw = pidx % NPATCH;
  int ph = hw / 14, pw = hw % 14;
  int t = threadIdx.x;
  float v[3];
#pragma unroll
  for (int u = 0; u < 3; ++u) {
    int k = t + u * 256;                  // feature index (p1*16+p2)*3 + c
    int c = k % 3, p2 = (k / 3) & 15, p1 = k / 48;
    v[u] = img[(((size_t)b * 3 + c) * 224 + ph * 16 + p1) * 224 + pw * 16 + p2];
  }
  float mean, rstd;
  block_mean_rstd(v[0] + v[1] + v[2], v[0] * v[0] + v[1] * v[1] + v[2] * v[2], mean, rstd);
  ushort* o = xp + (size_t)pidx * 768;
#pragma unroll
  for (int u = 0; u < 3; ++u) { int k = t + u * 256; o[k] = f2b((v[u] - mean) * rstd * g[k] + bta[k]); }
}

// ---------------- LN2 + pos_emb, scatter into x (bf16) at token 1+i ----------------
__global__ __launch_bounds__(256) void ln2_pos(const float* __restrict__ xe,
                                               const float* __restrict__ g,
                                               const float* __restrict__ bta,
                                               const float* __restrict__ pos,
                                               ushort* __restrict__ x) {
  int pidx = blockIdx.x;
  int b = pidx / NPATCH, i = pidx % NPATCH;
  const float* xr = xe + (size_t)pidx * 768;
  int t = threadIdx.x;
  float v0 = xr[t], v1 = xr[t + 256], v2 = xr[t + 512];
  float mean, rstd;
  block_mean_rstd(v0 + v1 + v2, v0 * v0 + v1 * v1 + v2 * v2, mean, rstd);
  const float* p = pos + (size_t)(1 + i) * 768;
  ushort* o = x + ((size_t)b * NTOK + 1 + i) * 768;
  o[t]       = f2b((v0 - mean) * rstd * g[t]       + bta[t]       + p[t]);
  o[t + 256] = f2b((v1 - mean) * rstd * g[t + 256] + bta[t + 256] + p[t + 256]);
  o[t + 512] = f2b((v2 - mean) * rstd * g[t + 512] + bta[t + 512] + p[t + 512]);
}

// ---------------- cls token + pos_emb[0] (bf16 out) ----------------
__global__ __launch_bounds__(256) void cls_init(const float* __restrict__ cls_tok,
                                                const float* __restrict__ pos,
                                                ushort* __restrict__ x) {
  int b = blockIdx.x, t = threadIdx.x;
  ushort* o = x + (size_t)b * NTOK * 768;
#pragma unroll
  for (int u = 0; u < 3; ++u) { int k = t + u * 256; o[k] = f2b(cls_tok[k] + pos[k]); }
}

// ---------------- cast + transpose: W fp32 [K][N] -> Wt bf16 [N][K] (bounds-checked) ----------------
__global__ __launch_bounds__(256) void transpose_cast(const float* __restrict__ W,
                                                      ushort* __restrict__ Wt,
                                                      int K, int N) {
  __shared__ float t[32][33];
  int n0 = blockIdx.x * 32, k0 = blockIdx.y * 32;
  int tx = threadIdx.x, ty = threadIdx.y;   // 32 x 8
#pragma unroll
  for (int u = 0; u < 32; u += 8) {
    int n = n0 + tx;
    t[ty + u][tx] = (n < N) ? W[(size_t)(k0 + ty + u) * N + n] : 0.f;
  }
  __syncthreads();
#pragma unroll
  for (int u = 0; u < 32; u += 8) {
    int n = n0 + ty + u;
    if (n < N) Wt[(size_t)n * K + k0 + tx] = f2b(t[tx][ty + u]);
  }
}

// ---------------- 64x64 vectorized transpose (dims % 64 == 0), flat 256 thr ----------------
__device__ __forceinline__ void transpose_layer64(int bid,
                                                  const float* wq, const float* wo,
                                                  const float* w1, const float* w2,
                                                  ushort* tq, ushort* to,
                                                  ushort* t1, ushort* t2) {
  const float* W; ushort* Wt; int K, N, xt;
  if (bid < 432)       {             W = wq; Wt = tq; K = 768;  N = 2304; xt = 36; }
  else if (bid < 576)  { bid -= 432; W = wo; Wt = to; K = 768;  N = 768;  xt = 12; }
  else if (bid < 1152) { bid -= 576; W = w1; Wt = t1; K = 768;  N = 3072; xt = 48; }
  else                 { bid -= 1152; W = w2; Wt = t2; K = 3072; N = 768; xt = 12; }
  int n0 = (bid % xt) * 64, k0 = (bid / xt) * 64;
  __shared__ float t[64][65];
  int id = threadIdx.x;
  int tx = id & 15, ty = id >> 4;           // load: 16 lanes x 16 rows per pass
#pragma unroll
  for (int u = 0; u < 4; ++u) {
    int k = ty + 16 * u;
    f32x4 v = *(const f32x4*)(W + (size_t)(k0 + k) * N + n0 + tx * 4);
    t[k][tx * 4 + 0] = v[0]; t[k][tx * 4 + 1] = v[1];
    t[k][tx * 4 + 2] = v[2]; t[k][tx * 4 + 3] = v[3];
  }
  __syncthreads();
  int wx = id & 31, wy = id >> 5;           // write: 32 lanes x 8 n-rows per pass
#pragma unroll
  for (int u = 0; u < 8; ++u) {
    int n = wy + 8 * u;
    u16x2 o = { f2b(t[wx * 2][n]), f2b(t[wx * 2 + 1][n]) };
    *(u16x2*)(Wt + (size_t)(n0 + n) * K + k0 + wx * 2) = o;
  }
}

__global__ __launch_bounds__(256) void transpose4(const float* __restrict__ wq,
                                                  const float* __restrict__ wo,
                                                  const float* __restrict__ w1,
                                                  const float* __restrict__ w2,
                                                  ushort* __restrict__ tq,
                                                  ushort* __restrict__ to,
                                                  ushort* __restrict__ t1,
                                                  ushort* __restrict__ t2) {
  transpose_layer64(blockIdx.x, wq, wo, w1, w2, tq, to, t1, t2);
}

__global__ __launch_bounds__(256) void transpose_all(const float* __restrict__ wq,
                                                     const float* __restrict__ wo,
                                                     const float* __restrict__ w1,
                                                     const float* __restrict__ w2,
                                                     ushort* __restrict__ tq,
                                                     ushort* __restrict__ to,
                                                     ushort* __restrict__ t1,
                                                     ushort* __restrict__ t2) {
  int l = blockIdx.x / 1728, bid = blockIdx.x % 1728;
  transpose_layer64(bid,
                    wq + (size_t)l * 768 * 2304, wo + (size_t)l * 768 * 768,
                    w1 + (size_t)l * 768 * MFF,  w2 + (size_t)l * MFF * 768,
                    tq + (size_t)l * 2304 * 768, to + (size_t)l * 768 * 768,
                    t1 + (size_t)l * MFF * 768,  t2 + (size_t)l * 768 * MFF);
}

// ================= bf16 MFMA GEMM v6: 2-buf counted-vmcnt (128x128) =================
// For N=768-class GEMMs (small grids).
template<int EP, int RESID, int OBF>
__global__ __launch_bounds__(256, 4) void gemm_v6(const ushort* __restrict__ A,
                                                  const ushort* __restrict__ Bt,
                                                  const float* __restrict__ bias,
                                                  const void* __restrict__ resid,
                                                  void* __restrict__ Cv,
                                                  int M, int N, int K) {
  __shared__ ushort smem[2 * 8192];

  const int tid = threadIdx.x;
  const int w = tid >> 6, l = tid & 63;
  const int fr = l & 15, fc = l >> 4;

  const int ntx = gridDim.x;
  const int nwg = ntx * gridDim.y;
  const int orig = blockIdx.y * ntx + blockIdx.x;
  const int q = nwg >> 3, r = nwg & 7, xcd = orig & 7, idx = orig >> 3;
  const int wg = (xcd < r ? xcd * (q + 1) : r * (q + 1) + (xcd - r) * q) + idx;
  const int row0 = (wg / ntx) * 128, col0 = (wg % ntx) * 128;

  const int wr = (w >> 1) * 64, wc = (w & 1) * 64;

  const int srow = tid >> 2;
  const int sg = (tid & 3) ^ ((srow >> 1) & 3);
  const ushort* pA0 = A  + (size_t)(row0 + srow) * K + sg * 8;
  const ushort* pA1 = A  + (size_t)(row0 + 64 + srow) * K + sg * 8;
  const ushort* pB0 = Bt + (size_t)(col0 + srow) * K + sg * 8;
  const ushort* pB1 = Bt + (size_t)(col0 + 64 + srow) * K + sg * 8;

  auto stage = [&](int t_, ushort* dst) {
    const int k0 = t_ * 32;
    gload16(pA0 + k0, dst + tid * 8);
    gload16(pA1 + k0, dst + (tid + 256) * 8);
    gload16(pB0 + k0, dst + 4096 + tid * 8);
    gload16(pB1 + k0, dst + 4096 + (tid + 256) * 8);
  };

  int idxA[4], idxB[4];
#pragma unroll
  for (int m = 0; m < 4; ++m) {
    int rA = wr + m * 16 + fr;
    idxA[m] = rA * 32 + ((fc ^ ((rA >> 1) & 3)) << 3);
  }
#pragma unroll
  for (int n = 0; n < 4; ++n) {
    int rB = wc + n * 16 + fr;
    idxB[n] = rB * 32 + ((fc ^ ((rB >> 1) & 3)) << 3);
  }

  f32x4 acc[4][4] = {};

  auto compute = [&](const ushort* As) {
    const ushort* Bs = As + 4096;
    bf16x8 a_[4], b_[4];
#pragma unroll
    for (int m = 0; m < 4; ++m) a_[m] = *(const bf16x8*)(As + idxA[m]);
#pragma unroll
    for (int n = 0; n < 4; ++n) b_[n] = *(const bf16x8*)(Bs + idxB[n]);
#pragma unroll
    for (int m = 0; m < 4; ++m)
#pragma unroll
      for (int n = 0; n < 4; ++n)
        acc[m][n] = __builtin_amdgcn_mfma_f32_16x16x32_bf16(b_[n], a_[m], acc[m][n], 0, 0, 0);
  };

#define VM4() asm volatile("s_waitcnt vmcnt(4)" ::: "memory")
#define VM0() asm volatile("s_waitcnt vmcnt(0)" ::: "memory")

  const int NT = K >> 5;

  stage(0, smem);
  for (int t = 0; t < NT; t += 2) {
    if (t + 1 < NT) { stage(t + 1, smem + 8192); VM4(); } else VM0();
    __builtin_amdgcn_s_barrier();
    compute(smem);
    __builtin_amdgcn_s_barrier();
    if (t + 1 < NT) {
      if (t + 2 < NT) { stage(t + 2, smem); VM4(); } else VM0();
      __builtin_amdgcn_s_barrier();
      compute(smem + 8192);
      __builtin_amdgcn_s_barrier();
    }
  }
#undef VM4
#undef VM0

  if (!OBF) {
    float* Cf = (float*)Cv;
#pragma unroll
    for (int m = 0; m < 4; ++m) {
      int row = row0 + wr + m * 16 + fr;
      if (row >= M) continue;
#pragma unroll
      for (int n = 0; n < 4; ++n) {
        int col = col0 + wc + n * 16 + fc * 4;
        f32x4 v = acc[m][n];
        if (bias) v += *(const f32x4*)(bias + col);
        if (EP) {
#pragma unroll
          for (int rr = 0; rr < 4; ++rr) v[rr] = gelu_f(v[rr]);
        }
        if (RESID) v += *(const f32x4*)((const float*)resid + (size_t)row * N + col);
        *(f32x4*)(Cf + (size_t)row * N + col) = v;
      }
    }
  } else {
    __syncthreads();
    ushort* Cw = smem + w * 4096;
#pragma unroll
    for (int m = 0; m < 4; ++m) {
      int rl = m * 16 + fr;
      int row = row0 + wr + rl;
#pragma unroll
      for (int n = 0; n < 4; ++n) {
        int col = col0 + wc + n * 16 + fc * 4;
        f32x4 v = acc[m][n];
        if (bias) v += *(const f32x4*)(bias + col);
        if (EP) {
#pragma unroll
          for (int rr = 0; rr < 4; ++rr) v[rr] = gelu_f(v[rr]);
        }
        if (RESID) {
          u16x4 rv = *(const u16x4*)((const ushort*)resid + (size_t)row * N + col);
#pragma unroll
          for (int rr = 0; rr < 4; ++rr) v[rr] += b2f(rv[rr]);
        }
        u16x4 pk = { f2b(v[0]), f2b(v[1]), f2b(v[2]), f2b(v[3]) };
        int s = (n * 4 + fc) ^ (rl & 7);
        *(u16x4*)(Cw + rl * 64 + s * 4) = pk;
      }
    }
    ushort* Cb = (ushort*)Cv;
#pragma unroll
    for (int pp = 0; pp < 16; ++pp) {
      int rl = pp * 4 + (l >> 4);
      int cs = l & 15;
      u16x4 pk = *(const u16x4*)(Cw + rl * 64 + ((cs ^ (rl & 7)) * 4));
      int row = row0 + wr + rl;
      if (row < M) *(u16x4*)(Cb + (size_t)row * N + col0 + wc + cs * 4) = pk;
    }
  }
}

// ================= bf16 MFMA GEMM v8: 256x256 tile, 512 thr, 3-buf counted =================
// Arithmetic-intensity fix: 128 FLOP per L2-byte (v6: 64). 8 waves (4Mx2N), wave 64x128
// (128 acc). BK=32, 3 LDS bufs (96KB dynamic), v4's proven 1-barrier schedule:
//   iter t: stage(t+2 -> buf[(t+2)%3]); compute(buf[t%3]); vmcnt(4); barrier.
// vmcnt(4) waits loads issued 2 iters ago (~2 periods cover). For LARGE grids only.
template<int EP, int RESID, int OBF>
__global__ __launch_bounds__(512, 1) void gemm_v8(const ushort* __restrict__ A,
                                                  const ushort* __restrict__ Bt,
                                                  const float* __restrict__ bias,
                                                  const void* __restrict__ resid,
                                                  void* __restrict__ Cv,
                                                  int M, int N, int K) {
  extern __shared__ ushort smem[];          // 3 bufs x 16384 elems (As 8192 | Bs 8192)

  const int tid = threadIdx.x;
  const int w = tid >> 6, l = tid & 63;
  const int fr = l & 15, fc = l >> 4;

  const int ntx = gridDim.x;
  const int nwg = ntx * gridDim.y;
  const int orig = blockIdx.y * ntx + blockIdx.x;
  const int q = nwg >> 3, r = nwg & 7, xcd = orig & 7, idx = orig >> 3;
  const int wg = (xcd < r ? xcd * (q + 1) : r * (q + 1) + (xcd - r) * q) + idx;
  const int row0 = (wg / ntx) * 256, col0 = (wg % ntx) * 256;

  const int wrow = (w >> 1) * 64, wcol = (w & 1) * 128;

  // staging: A/B each 256 rows x 4 chunks = 1024 chunks; thread does c=tid, tid+512.
  // row = c>>2, slot g = c&3 holds global chunk g^((row>>1)&3); row+128 same sg.
  const int srow = tid >> 2;                // 0..127
  const int sg = (tid & 3) ^ ((srow >> 1) & 3);
  const ushort* pA0 = A  + (size_t)(row0 + srow) * K + sg * 8;
  const ushort* pA1 = A  + (size_t)(row0 + 128 + srow) * K + sg * 8;
  const ushort* pB0 = Bt + (size_t)(col0 + srow) * K + sg * 8;
  const ushort* pB1 = Bt + (size_t)(col0 + 128 + srow) * K + sg * 8;

  auto stage = [&](int t_, ushort* dst) {   // 4 loads/thread
    const int k0 = t_ * 32;
    gload16(pA0 + k0, dst + tid * 8);
    gload16(pA1 + k0, dst + (tid + 512) * 8);
    gload16(pB0 + k0, dst + 8192 + tid * 8);
    gload16(pB1 + k0, dst + 8192 + (tid + 512) * 8);
  };

  int idxA[4], idxB[8];
#pragma unroll
  for (int m = 0; m < 4; ++m) {
    int rA = wrow + m * 16 + fr;
    idxA[m] = rA * 32 + ((fc ^ ((rA >> 1) & 3)) << 3);
  }
#pragma unroll
  for (int n = 0; n < 8; ++n) {
    int rB = wcol + n * 16 + fr;
    idxB[n] = rB * 32 + ((fc ^ ((rB >> 1) & 3)) << 3);
  }

  f32x4 acc[4][8] = {};

  auto compute = [&](const ushort* As) {
    const ushort* Bs = As + 8192;
    bf16x8 a_[4], b_[8];
#pragma unroll
    for (int m = 0; m < 4; ++m) a_[m] = *(const bf16x8*)(As + idxA[m]);
#pragma unroll
    for (int n = 0; n < 8; ++n) b_[n] = *(const bf16x8*)(Bs + idxB[n]);
#pragma unroll
    for (int m = 0; m < 4; ++m)
#pragma unroll
      for (int n = 0; n < 8; ++n)
        acc[m][n] = __builtin_amdgcn_mfma_f32_16x16x32_bf16(b_[n], a_[m], acc[m][n], 0, 0, 0);
  };

#define VM4() asm volatile("s_waitcnt vmcnt(4)" ::: "memory")
#define VM0() asm volatile("s_waitcnt vmcnt(0)" ::: "memory")

  const int NT = K >> 5;        // 24 for K=768

  // prologue: 2 stages in flight, wait for the first
  stage(0, smem);
  stage(1, smem + 16384);
  VM4();
  __builtin_amdgcn_s_barrier();

  int bi = 0, si = 2;
  for (int t = 0; t < NT; ++t) {
    const bool more2 = (t + 2 < NT);
    if (more2) stage(t + 2, smem + si * 16384);
    compute(smem + bi * 16384);
    if (t + 1 < NT) {
      if (more2) VM4(); else VM0();
      __builtin_amdgcn_s_barrier();
    }
    bi = (bi == 2) ? 0 : bi + 1;
    si = (si == 2) ? 0 : si + 1;
  }
#undef VM4
#undef VM0

  if (!OBF) {
    float* Cf = (float*)Cv;
#pragma unroll
    for (int m = 0; m < 4; ++m) {
      int row = row0 + wrow + m * 16 + fr;
      if (row >= M) continue;
#pragma unroll
      for (int n = 0; n < 8; ++n) {
        int col = col0 + wcol + n * 16 + fc * 4;
        f32x4 v = acc[m][n];
        if (bias) v += *(const f32x4*)(bias + col);
        if (EP) {
#pragma unroll
          for (int rr = 0; rr < 4; ++rr) v[rr] = gelu_f(v[rr]);
        }
        if (RESID) v += *(const f32x4*)((const float*)resid + (size_t)row * N + col);
        *(f32x4*)(Cf + (size_t)row * N + col) = v;
      }
    }
  } else {
    // bf16 out: per-wave LDS restage (8KB/wave region) in two 32-row passes
    __syncthreads();
    ushort* Cw = smem + w * 4096;
    ushort* Cb = (ushort*)Cv;
#pragma unroll
    for (int mp = 0; mp < 2; ++mp) {
#pragma unroll
      for (int m2 = 0; m2 < 2; ++m2) {
        int m = mp * 2 + m2;
        int rl = m2 * 16 + fr;
#pragma unroll
        for (int n = 0; n < 8; ++n) {
          int col = col0 + wcol + n * 16 + fc * 4;
          f32x4 v = acc[m][n];
          if (bias) v += *(const f32x4*)(bias + col);
          if (EP) {
#pragma unroll
            for (int rr = 0; rr < 4; ++rr) v[rr] = gelu_f(v[rr]);
          }
          u16x4 pk = { f2b(v[0]), f2b(v[1]), f2b(v[2]), f2b(v[3]) };
          int s = (n * 4 + fc) ^ (rl & 7);
          *(u16x4*)(Cw + rl * 128 + s * 4) = pk;
        }
      }
      asm volatile("s_waitcnt lgkmcnt(0)" ::: "memory");
#pragma unroll
      for (int pp = 0; pp < 16; ++pp) {
        int rl = pp * 2 + (l >> 5);
        int cs = l & 31;
        u16x4 pk = *(const u16x4*)(Cw + rl * 128 + ((cs ^ (rl & 7)) * 4));
        int row = row0 + wrow + mp * 32 + rl;
        if (row < M) *(u16x4*)(Cb + (size_t)row * N + col0 + wcol + cs * 4) = pk;
      }
      asm volatile("s_waitcnt lgkmcnt(0)" ::: "memory");   // WAR before next pass
    }
  }
}

// ---------------- 128x128 bf16 MFMA GEMM (head only, N-bounds-safe) ----------------
template<int EP, int RESID, int OBF>
__global__ __launch_bounds__(256) void gemm_bt(const ushort* __restrict__ A,
                                               const ushort* __restrict__ Bt,
                                               const float* __restrict__ bias,
                                               const float* __restrict__ resid,
                                               void* __restrict__ C,
                                               int M, int N, int K) {
  __shared__ ushort As[128 * 32];
  __shared__ ushort Bs[128 * 32];
  int tid = threadIdx.x;
  int w = tid >> 6, l = tid & 63;
  int fr = l & 15, fc = l >> 4;
  int row0 = blockIdx.y * 128, col0 = blockIdx.x * 128;
  int wr = (w >> 1) * 64, wc = (w & 1) * 64;

  int srow0 = w * 32 + (l >> 2);
  int srow1 = srow0 + 16;
  int sc0 = (((l & 3) ^ ((srow0 >> 1) & 3)) << 3);
  int sc1 = (((l & 3) ^ ((srow1 >> 1) & 3)) << 3);
  const ushort* ga0 = A  + (size_t)(row0 + srow0) * K + sc0;
  const ushort* ga1 = A  + (size_t)(row0 + srow1) * K + sc1;
  const ushort* gb0 = Bt + (size_t)(col0 + srow0) * K + sc0;
  const ushort* gb1 = Bt + (size_t)(col0 + srow1) * K + sc1;

  int idxA[4], idxB[4];
#pragma unroll
  for (int m = 0; m < 4; ++m) {
    int rA = wr + m * 16 + fr;
    idxA[m] = rA * 32 + ((fc ^ ((rA >> 1) & 3)) << 3);
  }
#pragma unroll
  for (int n = 0; n < 4; ++n) {
    int rB = wc + n * 16 + fr;
    idxB[n] = rB * 32 + ((fc ^ ((rB >> 1) & 3)) << 3);
  }

  f32x4 acc[4][4] = {};

  for (int k0 = 0; k0 < K; k0 += 32) {
    gload16(ga0 + k0, &As[w * 1024]);
    gload16(ga1 + k0, &As[w * 1024 + 512]);
    gload16(gb0 + k0, &Bs[w * 1024]);
    gload16(gb1 + k0, &Bs[w * 1024 + 512]);
    __syncthreads();
    bf16x8 af[4], bfr[4];
#pragma unroll
    for (int m = 0; m < 4; ++m) af[m] = *(const bf16x8*)(As + idxA[m]);
#pragma unroll
    for (int n = 0; n < 4; ++n) bfr[n] = *(const bf16x8*)(Bs + idxB[n]);
#pragma unroll
    for (int m = 0; m < 4; ++m)
#pragma unroll
      for (int n = 0; n < 4; ++n)
        acc[m][n] = __builtin_amdgcn_mfma_f32_16x16x32_bf16(af[m], bfr[n], acc[m][n], 0, 0, 0);
    __syncthreads();
  }

#pragma unroll
  for (int n = 0; n < 4; ++n) {
    int col = col0 + wc + n * 16 + fr;
    if (col >= N) continue;
    float bv = bias ? bias[col] : 0.f;
#pragma unroll
    for (int m = 0; m < 4; ++m) {
#pragma unroll
      for (int rr = 0; rr < 4; ++rr) {
        int row = row0 + wr + m * 16 + fc * 4 + rr;
        if (row >= M) continue;
        float v = acc[m][n][rr] + bv;
        if (EP == 1) v = 0.5f * v * (1.0f + erff(v * 0.70710678118654752f));
        if (RESID) v += resid[(size_t)row * N + col];
        if (OBF) ((ushort*)C)[(size_t)row * N + col] = f2b(v);
        else     ((float*)C)[(size_t)row * N + col]  = v;
      }
    }
  }
}

// ---------------- MFMA flash attention ----------------
__global__ __launch_bounds__(256) void attn_mfma(const ushort* __restrict__ qkv,
                                                 ushort* __restrict__ aout) {
  int bid = blockIdx.x;
  int qt = bid & 3;
  int h  = (bid >> 2) % NH;
  int b  = (bid >> 2) / NH;
  int tid = threadIdx.x, w = tid >> 6, l = tid & 63;
  int fr = l & 15, fc = l >> 4;

  __shared__ ushort Vt[64 * 64];        // swizzled V^T tile [d][key]
  __shared__ ushort Pl[4 * 16 * 64];    // per-wave P [qrow][key], swizzled

  const size_t brow = (size_t)b * NTOK;
  int q0 = qt * 64 + w * 16;

  bf16x8 qf[2];
  {
    const ushort* qp = qkv + (brow + q0 + fr) * 2304 + h * 64 + fc * 8;
    qf[0] = *(const bf16x8*)qp;
    qf[1] = *(const bf16x8*)(qp + 32);
  }
  float rs[4] = {0.f, 0.f, 0.f, 0.f};
  f32x4 oc[4] = {};

  for (int kt = 0; kt < 4; ++kt) {
    __syncthreads();
    {
      int key = tid >> 2, d0 = (tid & 3) * 16;
      int j = kt * 64 + key;
      bool valid = j < NTOK;
      const ushort* vp = qkv + (brow + j) * 2304 + 1536 + h * 64 + d0;
      ushort vbuf[16];
      if (valid) {
        *(bf16x8*)(vbuf)     = *(const bf16x8*)vp;
        *(bf16x8*)(vbuf + 8) = *(const bf16x8*)(vp + 8);
      } else {
#pragma unroll
        for (int i = 0; i < 16; ++i) vbuf[i] = 0;
      }
#pragma unroll
      for (int i = 0; i < 16; ++i) {
        int d = d0 + i;
        int byte = d * 128 + ((((key >> 3)) ^ (d & 7)) << 4) + (key & 7) * 2;
        Vt[byte >> 1] = vbuf[i];
      }
    }
    f32x4 sc[4];
#pragma unroll
    for (int n = 0; n < 4; ++n) {
      f32x4 z = {};
      const ushort* kp = qkv + (brow + kt * 64 + n * 16 + fr) * 2304 + 768 + h * 64 + fc * 8;
      bf16x8 k0 = *(const bf16x8*)kp;
      bf16x8 k1 = *(const bf16x8*)(kp + 32);
      z = __builtin_amdgcn_mfma_f32_16x16x32_bf16(qf[0], k0, z, 0, 0, 0);
      z = __builtin_amdgcn_mfma_f32_16x16x32_bf16(qf[1], k1, z, 0, 0, 0);
      sc[n] = z;
    }
    float part[4] = {0.f, 0.f, 0.f, 0.f};
#pragma unroll
    for (int n = 0; n < 4; ++n) {
      int j = kt * 64 + n * 16 + fr;
      bool jv = j < NTOK;
#pragma unroll
      for (int rr = 0; rr < 4; ++rr) {
        float e = jv ? __expf(sc[n][rr] * 0.125f) : 0.f;
        part[rr] += e;
        int row = fc * 4 + rr, col = n * 16 + fr;
        int byte = row * 128 + (((col >> 3) ^ (row & 7)) << 4) + (col & 7) * 2;
        Pl[w * 1024 + (byte >> 1)] = f2b(e);
      }
    }
#pragma unroll
    for (int rr = 0; rr < 4; ++rr) {
      float p = part[rr];
      p += __shfl_xor(p, 1); p += __shfl_xor(p, 2);
      p += __shfl_xor(p, 4); p += __shfl_xor(p, 8);
      rs[rr] += p;
    }
    __syncthreads();
#pragma unroll
    for (int ks = 0; ks < 2; ++ks) {
      int prow = fr;
      int pbyte = prow * 128 + (((ks * 4 + fc) ^ (prow & 7)) << 4);
      bf16x8 pf = *(const bf16x8*)(Pl + w * 1024 + (pbyte >> 1));
#pragma unroll
      for (int n = 0; n < 4; ++n) {
        int d = n * 16 + fr;
        int vb = d * 128 + (((ks * 4 + fc) ^ (d & 7)) << 4);
        bf16x8 vf = *(const bf16x8*)(Vt + (vb >> 1));
        oc[n] = __builtin_amdgcn_mfma_f32_16x16x32_bf16(pf, vf, oc[n], 0, 0, 0);
      }
    }
  }
#pragma unroll
  for (int n = 0; n < 4; ++n) {
#pragma unroll
    for (int rr = 0; rr < 4; ++rr) {
      int qq = q0 + fc * 4 + rr;
      if (qq < NTOK) {
        float v = oc[n][rr] / (rs[rr] + 1e-8f);
        aout[(brow + qq) * 768 + h * 64 + n * 16 + fr] = f2b(v);
      }
    }
  }
}

// ---------------- host launch ----------------
extern "C" void kernel_launch(void* const* d_in, const int* in_sizes, int n_in,
                              void* d_out, int out_size, void* d_ws, size_t ws_size,
                              hipStream_t stream) {
  const float* img       = (const float*)d_in[0];
  const float* p_ln1_g   = (const float*)d_in[1];
  const float* p_ln1_b   = (const float*)d_in[2];
  const float* patch_w   = (const float*)d_in[3];
  const float* patch_b   = (const float*)d_in[4];
  const float* p_ln2_g   = (const float*)d_in[5];
  const float* p_ln2_b   = (const float*)d_in[6];
  const float* pos_emb   = (const float*)d_in[7];
  const float* cls_tok   = (const float*)d_in[8];
  const float* attn_ln_g = (const float*)d_in[9];
  const float* attn_ln_b = (const float*)d_in[10];
  const float* w_qkv     = (const float*)d_in[11];
  const float* w_out     = (const float*)d_in[12];
  const float* b_out     = (const float*)d_in[13];
  const float* ff_ln_g   = (const float*)d_in[14];
  const float* ff_ln_b   = (const float*)d_in[15];
  const float* ff_w1     = (const float*)d_in[16];
  const float* ff_b1     = (const float*)d_in[17];
  const float* ff_w2     = (const float*)d_in[18];
  const float* ff_b2     = (const float*)d_in[19];
  const float* fin_ln_g  = (const float*)d_in[20];
  const float* fin_ln_b  = (const float*)d_in[21];
  const float* head_w    = (const float*)d_in[22];
  const float* head_b    = (const float*)d_in[23];
  float* out = (float*)d_out;

  (void)hipFuncSetAttribute((const void*)gemm_v8<0, 0, 1>,
                            hipFuncAttributeMaxDynamicSharedMemorySize, 98304);
  (void)hipFuncSetAttribute((const void*)gemm_v8<1, 0, 1>,
                            hipFuncAttributeMaxDynamicSharedMemorySize, 98304);

  // ---- workspace carve ----
  char* p = (char*)d_ws;
  auto alloc = [&](size_t bytes) { char* r = p; p += (bytes + 255) & ~(size_t)255; return r; };
  ushort* x      = (ushort*)alloc((size_t)ROWS_PAD * 768 * 2);    // bf16 residual stream
  ushort* xnb    = (ushort*)alloc((size_t)ROWS_PAD * 768 * 2);
  ushort* qkvb   = (ushort*)alloc((size_t)ROWS_PAD * 2304 * 2);
  ushort* aoutb  = (ushort*)alloc((size_t)ROWS_PAD * 768 * 2);
  ushort* pwt    = (ushort*)alloc((size_t)768 * 768 * 2);
  ushort* hwt    = (ushort*)alloc((size_t)1024 * 768 * 2);
  ushort* xclsb  = (ushort*)alloc((size_t)128 * 768 * 2);
  ushort* hidb   = qkvb;                 // [ROWS_PAD][3072] aliases qkvb+aoutb
  ushort* xpb    = xnb;                  // patch LN1 out (12544 rows)
  float*  xe     = (float*)qkvb;         // patch GEMM out fp32 (pre-loop only)

  const size_t SQ = (size_t)2304 * 768, SO = (size_t)768 * 768, S1 = (size_t)MFF * 768;
  size_t used = (size_t)(p - (char*)d_ws);
  bool oneshot = (used + 12 * (SQ + SO + 2 * S1) * 2 + 4096) <= ws_size;
  int nw = oneshot ? 12 : 1;
  ushort* wtq = (ushort*)alloc(nw * SQ * 2);
  ushort* wto = (ushort*)alloc(nw * SO * 2);
  ushort* wt1 = (ushort*)alloc(nw * S1 * 2);
  ushort* wt2 = (ushort*)alloc(nw * S1 * 2);

  dim3 blk(256), blk8(512), tblk(32, 8);

  // ---- patch embedding ----
  transpose_cast<<<dim3(24, 24), tblk, 0, stream>>>(patch_w, pwt, 768, 768);
  transpose_cast<<<dim3(32, 24), tblk, 0, stream>>>(head_w, hwt, 768, 1000);
  if (oneshot)
    transpose_all<<<12 * 1728, blk, 0, stream>>>(w_qkv, w_out, ff_w1, ff_w2,
                                                 wtq, wto, wt1, wt2);
  patch_ln1<<<PROWS, blk, 0, stream>>>(img, p_ln1_g, p_ln1_b, xpb);
  gemm_v6<0, 0, 0><<<dim3(6, 98), blk, 0, stream>>>(xpb, pwt, patch_b, nullptr, xe,
                                                    PROWS, 768, 768);
  ln2_pos<<<PROWS, blk, 0, stream>>>(xe, p_ln2_g, p_ln2_b, pos_emb, x);
  cls_init<<<B_, blk, 0, stream>>>(cls_tok, pos_emb, x);

  for (int l = 0; l < NL; ++l) {
    ushort* tq = wtq + (oneshot ? (size_t)l * SQ : 0);
    ushort* to = wto + (oneshot ? (size_t)l * SO : 0);
    ushort* t1 = wt1 + (oneshot ? (size_t)l * S1 : 0);
    ushort* t2 = wt2 + (oneshot ? (size_t)l * S1 : 0);
    if (!oneshot)
      transpose4<<<1728, blk, 0, stream>>>(w_qkv + (size_t)l * 768 * 2304,
                                           w_out + (size_t)l * 768 * 768,
                                           ff_w1 + (size_t)l * 768 * MFF,
                                           ff_w2 + (size_t)l * MFF * 768,
                                           tq, to, t1, t2);

    ln_rows_b<<<ROWS, blk, 0, stream>>>(x, 768, attn_ln_g + (size_t)l * 768,
                                        attn_ln_b + (size_t)l * 768, xnb);
    gemm_v8<0, 0, 1><<<dim3(9, 50), blk8, 98304, stream>>>(xnb, tq, nullptr, nullptr, qkvb,
                                                           ROWS, 2304, 768);
    attn_mfma<<<B_ * NH * 4, blk, 0, stream>>>(qkvb, aoutb);
    gemm_v6<0, 1, 1><<<dim3(6, 99), blk, 0, stream>>>(aoutb, to, b_out + (size_t)l * 768,
                                                      x, x, ROWS, 768, 768);
    ln_rows_b<<<ROWS, blk, 0, stream>>>(x, 768, ff_ln_g + (size_t)l * 768,
                                        ff_ln_b + (size_t)l * 768, xnb);
    gemm_v8<1, 0, 1><<<dim3(12, 50), blk8, 98304, stream>>>(xnb, t1, ff_b1 + (size_t)l * MFF,
                                                            nullptr, hidb, ROWS, MFF, 768);
    gemm_v6<0, 1, 1><<<dim3(6, 99), blk, 0, stream>>>(hidb, t2, ff_b2 + (size_t)l * 768,
                                                      x, x, ROWS, 768, MFF);
  }

  // ---- final LN (cls rows) + head ----
  ln_rows_b<<<B_, blk, 0, stream>>>(x, (long)NTOK * 768, fin_ln_g, fin_ln_b, xclsb);
  gemm_bt<0, 0, 0><<<dim3(8, 1), blk, 0, stream>>>(xclsb, hwt, head_b, nullptr, out,
                                                   B_, NCLS, 768);
}

// Round 17
// 4159.409 us; speedup vs baseline: 1.0605x; 1.0605x over previous
//
#include <hip/hip_runtime.h>
#include <hip/hip_bf16.h>
#include <math.h>

// ---- problem constants ----
#define B_     64
#define NTOK   197
#define NPATCH 196
#define D768   768
#define NL     12
#define NH     12
#define MFF    3072
#define NCLS   1000
#define ROWS   (B_ * NTOK)      // 12608
#define PROWS  (B_ * NPATCH)    // 12544
#define ROWS_PAD 12672          // 99 * 128

typedef unsigned short ushort;
typedef __bf16 bf16x8 __attribute__((ext_vector_type(8)));
typedef float  f32x4  __attribute__((ext_vector_type(4)));
typedef unsigned short u16x4 __attribute__((ext_vector_type(4)));
typedef unsigned short u16x2 __attribute__((ext_vector_type(2)));

__device__ __forceinline__ ushort f2b(float f) {
  __hip_bfloat16 h = __float2bfloat16(f);
  return *reinterpret_cast<ushort*>(&h);
}
__device__ __forceinline__ float b2f(ushort u) {
  unsigned int v = ((unsigned int)u) << 16;
  float f;
  __builtin_memcpy(&f, &v, 4);
  return f;
}

__device__ __forceinline__ void gload16(const ushort* g, ushort* lds) {
  __builtin_amdgcn_global_load_lds((const __attribute__((address_space(1))) void*)g,
                                   (__attribute__((address_space(3))) void*)lds, 16, 0, 0);
}

// tanh-form GELU via exp (max err ~1e-3, < bf16 quantization at those magnitudes)
__device__ __forceinline__ float gelu_f(float v) {
  float t = v * fmaf(0.0713548162726f, v * v, 1.5957691216f);
  return v / (1.0f + __expf(-t));
}

// ---------------- block-wide mean/rstd over 768 elems (256 threads) ----------------
__device__ __forceinline__ void block_mean_rstd(float s, float sq, float& mean, float& rstd) {
#pragma unroll
  for (int off = 32; off; off >>= 1) { s += __shfl_xor(s, off); sq += __shfl_xor(sq, off); }
  __shared__ float ss[4], ssq[4];
  int w = threadIdx.x >> 6;
  if ((threadIdx.x & 63) == 0) { ss[w] = s; ssq[w] = sq; }
  __syncthreads();
  s  = ss[0] + ss[1] + ss[2] + ss[3];
  sq = ssq[0] + ssq[1] + ssq[2] + ssq[3];
  mean = s * (1.0f / 768.0f);
  float var = sq * (1.0f / 768.0f) - mean * mean;
  rstd = rsqrtf(var + 1e-5f);
}

// ---------------- LN, wave-per-row: 4 rows/block, 12 bf16/lane, shfl-only reduce ----------------
__global__ __launch_bounds__(256) void ln_rows4(const ushort* __restrict__ in, long in_stride,
                                                const float* __restrict__ g,
                                                const float* __restrict__ bta,
                                                ushort* __restrict__ out) {
  const int w = threadIdx.x >> 6, l = threadIdx.x & 63;
  const size_t row = (size_t)blockIdx.x * 4 + w;
  const ushort* xr = in + row * in_stride;
  u16x4 xv[3];
  xv[0] = *(const u16x4*)(xr + l * 4);
  xv[1] = *(const u16x4*)(xr + 256 + l * 4);
  xv[2] = *(const u16x4*)(xr + 512 + l * 4);
  float v[12];
  float s = 0.f, sq = 0.f;
#pragma unroll
  for (int i = 0; i < 3; ++i)
#pragma unroll
    for (int j = 0; j < 4; ++j) {
      float f = b2f(xv[i][j]);
      v[i * 4 + j] = f;
      s += f; sq += f * f;
    }
#pragma unroll
  for (int off = 32; off; off >>= 1) { s += __shfl_xor(s, off); sq += __shfl_xor(sq, off); }
  float mean = s * (1.0f / 768.0f);
  float rstd = rsqrtf(sq * (1.0f / 768.0f) - mean * mean + 1e-5f);
  ushort* o = out + row * 768;
#pragma unroll
  for (int i = 0; i < 3; ++i) {
    int base = i * 256 + l * 4;
    f32x4 gv = *(const f32x4*)(g + base);
    f32x4 bv = *(const f32x4*)(bta + base);
    u16x4 ov = { f2b((v[i*4+0] - mean) * rstd * gv[0] + bv[0]),
                 f2b((v[i*4+1] - mean) * rstd * gv[1] + bv[1]),
                 f2b((v[i*4+2] - mean) * rstd * gv[2] + bv[2]),
                 f2b((v[i*4+3] - mean) * rstd * gv[3] + bv[3]) };
    *(u16x4*)(o + base) = ov;
  }
}

// ---------------- patch extraction + LN1 (bf16 out) ----------------
__global__ __launch_bounds__(256) void patch_ln1(const float* __restrict__ img,
                                                 const float* __restrict__ g,
                                                 const float* __restrict__ bta,
                                                 ushort* __restrict__ xp) {
  int pidx = blockIdx.x;                 // b*196 + ph*14 + pw
  int b = pidx / NPATCH, hw = pidx % NPATCH;
  int ph = hw / 14, pw = hw % 14;
  int t = threadIdx.x;
  float v[3];
#pragma unroll
  for (int u = 0; u < 3; ++u) {
    int k = t + u * 256;                  // feature index (p1*16+p2)*3 + c
    int c = k % 3, p2 = (k / 3) & 15, p1 = k / 48;
    v[u] = img[(((size_t)b * 3 + c) * 224 + ph * 16 + p1) * 224 + pw * 16 + p2];
  }
  float mean, rstd;
  block_mean_rstd(v[0] + v[1] + v[2], v[0] * v[0] + v[1] * v[1] + v[2] * v[2], mean, rstd);
  ushort* o = xp + (size_t)pidx * 768;
#pragma unroll
  for (int u = 0; u < 3; ++u) { int k = t + u * 256; o[k] = f2b((v[u] - mean) * rstd * g[k] + bta[k]); }
}

// ---------------- LN2 + pos_emb, scatter into x (bf16) at token 1+i ----------------
__global__ __launch_bounds__(256) void ln2_pos(const float* __restrict__ xe,
                                               const float* __restrict__ g,
                                               const float* __restrict__ bta,
                                               const float* __restrict__ pos,
                                               ushort* __restrict__ x) {
  int pidx = blockIdx.x;
  int b = pidx / NPATCH, i = pidx % NPATCH;
  const float* xr = xe + (size_t)pidx * 768;
  int t = threadIdx.x;
  float v0 = xr[t], v1 = xr[t + 256], v2 = xr[t + 512];
  float mean, rstd;
  block_mean_rstd(v0 + v1 + v2, v0 * v0 + v1 * v1 + v2 * v2, mean, rstd);
  const float* p = pos + (size_t)(1 + i) * 768;
  ushort* o = x + ((size_t)b * NTOK + 1 + i) * 768;
  o[t]       = f2b((v0 - mean) * rstd * g[t]       + bta[t]       + p[t]);
  o[t + 256] = f2b((v1 - mean) * rstd * g[t + 256] + bta[t + 256] + p[t + 256]);
  o[t + 512] = f2b((v2 - mean) * rstd * g[t + 512] + bta[t + 512] + p[t + 512]);
}

// ---------------- cls token + pos_emb[0] (bf16 out) ----------------
__global__ __launch_bounds__(256) void cls_init(const float* __restrict__ cls_tok,
                                                const float* __restrict__ pos,
                                                ushort* __restrict__ x) {
  int b = blockIdx.x, t = threadIdx.x;
  ushort* o = x + (size_t)b * NTOK * 768;
#pragma unroll
  for (int u = 0; u < 3; ++u) { int k = t + u * 256; o[k] = f2b(cls_tok[k] + pos[k]); }
}

// ---------------- cast + transpose: W fp32 [K][N] -> Wt bf16 [N][K] (bounds-checked) ----------------
__global__ __launch_bounds__(256) void transpose_cast(const float* __restrict__ W,
                                                      ushort* __restrict__ Wt,
                                                      int K, int N) {
  __shared__ float t[32][33];
  int n0 = blockIdx.x * 32, k0 = blockIdx.y * 32;
  int tx = threadIdx.x, ty = threadIdx.y;   // 32 x 8
#pragma unroll
  for (int u = 0; u < 32; u += 8) {
    int n = n0 + tx;
    t[ty + u][tx] = (n < N) ? W[(size_t)(k0 + ty + u) * N + n] : 0.f;
  }
  __syncthreads();
#pragma unroll
  for (int u = 0; u < 32; u += 8) {
    int n = n0 + ty + u;
    if (n < N) Wt[(size_t)n * K + k0 + tx] = f2b(t[tx][ty + u]);
  }
}

// ---------------- 64x64 vectorized transpose (dims % 64 == 0), flat 256 thr ----------------
__device__ __forceinline__ void transpose_layer64(int bid,
                                                  const float* wq, const float* wo,
                                                  const float* w1, const float* w2,
                                                  ushort* tq, ushort* to,
                                                  ushort* t1, ushort* t2) {
  const float* W; ushort* Wt; int K, N, xt;
  if (bid < 432)       {             W = wq; Wt = tq; K = 768;  N = 2304; xt = 36; }
  else if (bid < 576)  { bid -= 432; W = wo; Wt = to; K = 768;  N = 768;  xt = 12; }
  else if (bid < 1152) { bid -= 576; W = w1; Wt = t1; K = 768;  N = 3072; xt = 48; }
  else                 { bid -= 1152; W = w2; Wt = t2; K = 3072; N = 768; xt = 12; }
  int n0 = (bid % xt) * 64, k0 = (bid / xt) * 64;
  __shared__ float t[64][65];
  int id = threadIdx.x;
  int tx = id & 15, ty = id >> 4;           // load: 16 lanes x 16 rows per pass
#pragma unroll
  for (int u = 0; u < 4; ++u) {
    int k = ty + 16 * u;
    f32x4 v = *(const f32x4*)(W + (size_t)(k0 + k) * N + n0 + tx * 4);
    t[k][tx * 4 + 0] = v[0]; t[k][tx * 4 + 1] = v[1];
    t[k][tx * 4 + 2] = v[2]; t[k][tx * 4 + 3] = v[3];
  }
  __syncthreads();
  int wx = id & 31, wy = id >> 5;           // write: 32 lanes x 8 n-rows per pass
#pragma unroll
  for (int u = 0; u < 8; ++u) {
    int n = wy + 8 * u;
    u16x2 o = { f2b(t[wx * 2][n]), f2b(t[wx * 2 + 1][n]) };
    *(u16x2*)(Wt + (size_t)(n0 + n) * K + k0 + wx * 2) = o;
  }
}

__global__ __launch_bounds__(256) void transpose4(const float* __restrict__ wq,
                                                  const float* __restrict__ wo,
                                                  const float* __restrict__ w1,
                                                  const float* __restrict__ w2,
                                                  ushort* __restrict__ tq,
                                                  ushort* __restrict__ to,
                                                  ushort* __restrict__ t1,
                                                  ushort* __restrict__ t2) {
  transpose_layer64(blockIdx.x, wq, wo, w1, w2, tq, to, t1, t2);
}

__global__ __launch_bounds__(256) void transpose_all(const float* __restrict__ wq,
                                                     const float* __restrict__ wo,
                                                     const float* __restrict__ w1,
                                                     const float* __restrict__ w2,
                                                     ushort* __restrict__ tq,
                                                     ushort* __restrict__ to,
                                                     ushort* __restrict__ t1,
                                                     ushort* __restrict__ t2) {
  int l = blockIdx.x / 1728, bid = blockIdx.x % 1728;
  transpose_layer64(bid,
                    wq + (size_t)l * 768 * 2304, wo + (size_t)l * 768 * 768,
                    w1 + (size_t)l * 768 * MFF,  w2 + (size_t)l * MFF * 768,
                    tq + (size_t)l * 2304 * 768, to + (size_t)l * 768 * 768,
                    t1 + (size_t)l * MFF * 768,  t2 + (size_t)l * 768 * MFF);
}

// ================= bf16 MFMA GEMM v6: 2-buf counted-vmcnt (128x128) =================
// Best-measured GEMM family (R8/R10/R12). Swapped-operand MFMA, 0-conflict swizzle,
// __launch_bounds__(256,4), per half-iter: stage->vmcnt(4)->bar->compute->bar.
template<int EP, int RESID, int OBF>
__global__ __launch_bounds__(256, 4) void gemm_v6(const ushort* __restrict__ A,
                                                  const ushort* __restrict__ Bt,
                                                  const float* __restrict__ bias,
                                                  const void* __restrict__ resid,
                                                  void* __restrict__ Cv,
                                                  int M, int N, int K) {
  __shared__ ushort smem[2 * 8192];

  const int tid = threadIdx.x;
  const int w = tid >> 6, l = tid & 63;
  const int fr = l & 15, fc = l >> 4;

  const int ntx = gridDim.x;
  const int nwg = ntx * gridDim.y;
  const int orig = blockIdx.y * ntx + blockIdx.x;
  const int q = nwg >> 3, r = nwg & 7, xcd = orig & 7, idx = orig >> 3;
  const int wg = (xcd < r ? xcd * (q + 1) : r * (q + 1) + (xcd - r) * q) + idx;
  const int row0 = (wg / ntx) * 128, col0 = (wg % ntx) * 128;

  const int wr = (w >> 1) * 64, wc = (w & 1) * 64;

  const int srow = tid >> 2;
  const int sg = (tid & 3) ^ ((srow >> 1) & 3);
  const ushort* pA0 = A  + (size_t)(row0 + srow) * K + sg * 8;
  const ushort* pA1 = A  + (size_t)(row0 + 64 + srow) * K + sg * 8;
  const ushort* pB0 = Bt + (size_t)(col0 + srow) * K + sg * 8;
  const ushort* pB1 = Bt + (size_t)(col0 + 64 + srow) * K + sg * 8;

  auto stage = [&](int t_, ushort* dst) {
    const int k0 = t_ * 32;
    gload16(pA0 + k0, dst + tid * 8);
    gload16(pA1 + k0, dst + (tid + 256) * 8);
    gload16(pB0 + k0, dst + 4096 + tid * 8);
    gload16(pB1 + k0, dst + 4096 + (tid + 256) * 8);
  };

  int idxA[4], idxB[4];
#pragma unroll
  for (int m = 0; m < 4; ++m) {
    int rA = wr + m * 16 + fr;
    idxA[m] = rA * 32 + ((fc ^ ((rA >> 1) & 3)) << 3);
  }
#pragma unroll
  for (int n = 0; n < 4; ++n) {
    int rB = wc + n * 16 + fr;
    idxB[n] = rB * 32 + ((fc ^ ((rB >> 1) & 3)) << 3);
  }

  f32x4 acc[4][4] = {};

  auto compute = [&](const ushort* As) {
    const ushort* Bs = As + 4096;
    bf16x8 a_[4], b_[4];
#pragma unroll
    for (int m = 0; m < 4; ++m) a_[m] = *(const bf16x8*)(As + idxA[m]);
#pragma unroll
    for (int n = 0; n < 4; ++n) b_[n] = *(const bf16x8*)(Bs + idxB[n]);
#pragma unroll
    for (int m = 0; m < 4; ++m)
#pragma unroll
      for (int n = 0; n < 4; ++n)
        acc[m][n] = __builtin_amdgcn_mfma_f32_16x16x32_bf16(b_[n], a_[m], acc[m][n], 0, 0, 0);
  };

#define VM4() asm volatile("s_waitcnt vmcnt(4)" ::: "memory")
#define VM0() asm volatile("s_waitcnt vmcnt(0)" ::: "memory")

  const int NT = K >> 5;

  stage(0, smem);
  for (int t = 0; t < NT; t += 2) {
    if (t + 1 < NT) { stage(t + 1, smem + 8192); VM4(); } else VM0();
    __builtin_amdgcn_s_barrier();
    compute(smem);
    __builtin_amdgcn_s_barrier();
    if (t + 1 < NT) {
      if (t + 2 < NT) { stage(t + 2, smem); VM4(); } else VM0();
      __builtin_amdgcn_s_barrier();
      compute(smem + 8192);
      __builtin_amdgcn_s_barrier();
    }
  }
#undef VM4
#undef VM0

  if (!OBF) {
    float* Cf = (float*)Cv;
#pragma unroll
    for (int m = 0; m < 4; ++m) {
      int row = row0 + wr + m * 16 + fr;
      if (row >= M) continue;
#pragma unroll
      for (int n = 0; n < 4; ++n) {
        int col = col0 + wc + n * 16 + fc * 4;
        f32x4 v = acc[m][n];
        if (bias) v += *(const f32x4*)(bias + col);
        if (EP) {
#pragma unroll
          for (int rr = 0; rr < 4; ++rr) v[rr] = gelu_f(v[rr]);
        }
        if (RESID) v += *(const f32x4*)((const float*)resid + (size_t)row * N + col);
        *(f32x4*)(Cf + (size_t)row * N + col) = v;
      }
    }
  } else {
    __syncthreads();
    ushort* Cw = smem + w * 4096;
#pragma unroll
    for (int m = 0; m < 4; ++m) {
      int rl = m * 16 + fr;
      int row = row0 + wr + rl;
#pragma unroll
      for (int n = 0; n < 4; ++n) {
        int col = col0 + wc + n * 16 + fc * 4;
        f32x4 v = acc[m][n];
        if (bias) v += *(const f32x4*)(bias + col);
        if (EP) {
#pragma unroll
          for (int rr = 0; rr < 4; ++rr) v[rr] = gelu_f(v[rr]);
        }
        if (RESID) {
          u16x4 rv = *(const u16x4*)((const ushort*)resid + (size_t)row * N + col);
#pragma unroll
          for (int rr = 0; rr < 4; ++rr) v[rr] += b2f(rv[rr]);
        }
        u16x4 pk = { f2b(v[0]), f2b(v[1]), f2b(v[2]), f2b(v[3]) };
        int s = (n * 4 + fc) ^ (rl & 7);
        *(u16x4*)(Cw + rl * 64 + s * 4) = pk;
      }
    }
    ushort* Cb = (ushort*)Cv;
#pragma unroll
    for (int pp = 0; pp < 16; ++pp) {
      int rl = pp * 4 + (l >> 4);
      int cs = l & 15;
      u16x4 pk = *(const u16x4*)(Cw + rl * 64 + ((cs ^ (rl & 7)) * 4));
      int row = row0 + wr + rl;
      if (row < M) *(u16x4*)(Cb + (size_t)row * N + col0 + wc + cs * 4) = pk;
    }
  }
}

// ---------------- 128x128 bf16 MFMA GEMM (head only, N-bounds-safe) ----------------
template<int EP, int RESID, int OBF>
__global__ __launch_bounds__(256) void gemm_bt(const ushort* __restrict__ A,
                                               const ushort* __restrict__ Bt,
                                               const float* __restrict__ bias,
                                               const float* __restrict__ resid,
                                               void* __restrict__ C,
                                               int M, int N, int K) {
  __shared__ ushort As[128 * 32];
  __shared__ ushort Bs[128 * 32];
  int tid = threadIdx.x;
  int w = tid >> 6, l = tid & 63;
  int fr = l & 15, fc = l >> 4;
  int row0 = blockIdx.y * 128, col0 = blockIdx.x * 128;
  int wr = (w >> 1) * 64, wc = (w & 1) * 64;

  int srow0 = w * 32 + (l >> 2);
  int srow1 = srow0 + 16;
  int sc0 = (((l & 3) ^ ((srow0 >> 1) & 3)) << 3);
  int sc1 = (((l & 3) ^ ((srow1 >> 1) & 3)) << 3);
  const ushort* ga0 = A  + (size_t)(row0 + srow0) * K + sc0;
  const ushort* ga1 = A  + (size_t)(row0 + srow1) * K + sc1;
  const ushort* gb0 = Bt + (size_t)(col0 + srow0) * K + sc0;
  const ushort* gb1 = Bt + (size_t)(col0 + srow1) * K + sc1;

  int idxA[4], idxB[4];
#pragma unroll
  for (int m = 0; m < 4; ++m) {
    int rA = wr + m * 16 + fr;
    idxA[m] = rA * 32 + ((fc ^ ((rA >> 1) & 3)) << 3);
  }
#pragma unroll
  for (int n = 0; n < 4; ++n) {
    int rB = wc + n * 16 + fr;
    idxB[n] = rB * 32 + ((fc ^ ((rB >> 1) & 3)) << 3);
  }

  f32x4 acc[4][4] = {};

  for (int k0 = 0; k0 < K; k0 += 32) {
    gload16(ga0 + k0, &As[w * 1024]);
    gload16(ga1 + k0, &As[w * 1024 + 512]);
    gload16(gb0 + k0, &Bs[w * 1024]);
    gload16(gb1 + k0, &Bs[w * 1024 + 512]);
    __syncthreads();
    bf16x8 af[4], bfr[4];
#pragma unroll
    for (int m = 0; m < 4; ++m) af[m] = *(const bf16x8*)(As + idxA[m]);
#pragma unroll
    for (int n = 0; n < 4; ++n) bfr[n] = *(const bf16x8*)(Bs + idxB[n]);
#pragma unroll
    for (int m = 0; m < 4; ++m)
#pragma unroll
      for (int n = 0; n < 4; ++n)
        acc[m][n] = __builtin_amdgcn_mfma_f32_16x16x32_bf16(af[m], bfr[n], acc[m][n], 0, 0, 0);
    __syncthreads();
  }

#pragma unroll
  for (int n = 0; n < 4; ++n) {
    int col = col0 + wc + n * 16 + fr;
    if (col >= N) continue;
    float bv = bias ? bias[col] : 0.f;
#pragma unroll
    for (int m = 0; m < 4; ++m) {
#pragma unroll
      for (int rr = 0; rr < 4; ++rr) {
        int row = row0 + wr + m * 16 + fc * 4 + rr;
        if (row >= M) continue;
        float v = acc[m][n][rr] + bv;
        if (EP == 1) v = 0.5f * v * (1.0f + erff(v * 0.70710678118654752f));
        if (RESID) v += resid[(size_t)row * N + col];
        if (OBF) ((ushort*)C)[(size_t)row * N + col] = f2b(v);
        else     ((float*)C)[(size_t)row * N + col]  = v;
      }
    }
  }
}

// ---------------- MFMA flash attention ----------------
__global__ __launch_bounds__(256) void attn_mfma(const ushort* __restrict__ qkv,
                                                 ushort* __restrict__ aout) {
  int bid = blockIdx.x;
  int qt = bid & 3;
  int h  = (bid >> 2) % NH;
  int b  = (bid >> 2) / NH;
  int tid = threadIdx.x, w = tid >> 6, l = tid & 63;
  int fr = l & 15, fc = l >> 4;

  __shared__ ushort Vt[64 * 64];        // swizzled V^T tile [d][key]
  __shared__ ushort Pl[4 * 16 * 64];    // per-wave P [qrow][key], swizzled

  const size_t brow = (size_t)b * NTOK;
  int q0 = qt * 64 + w * 16;

  bf16x8 qf[2];
  {
    const ushort* qp = qkv + (brow + q0 + fr) * 2304 + h * 64 + fc * 8;
    qf[0] = *(const bf16x8*)qp;
    qf[1] = *(const bf16x8*)(qp + 32);
  }
  float rs[4] = {0.f, 0.f, 0.f, 0.f};
  f32x4 oc[4] = {};

  for (int kt = 0; kt < 4; ++kt) {
    __syncthreads();
    {
      int key = tid >> 2, d0 = (tid & 3) * 16;
      int j = kt * 64 + key;
      bool valid = j < NTOK;
      const ushort* vp = qkv + (brow + j) * 2304 + 1536 + h * 64 + d0;
      ushort vbuf[16];
      if (valid) {
        *(bf16x8*)(vbuf)     = *(const bf16x8*)vp;
        *(bf16x8*)(vbuf + 8) = *(const bf16x8*)(vp + 8);
      } else {
#pragma unroll
        for (int i = 0; i < 16; ++i) vbuf[i] = 0;
      }
#pragma unroll
      for (int i = 0; i < 16; ++i) {
        int d = d0 + i;
        int byte = d * 128 + ((((key >> 3)) ^ (d & 7)) << 4) + (key & 7) * 2;
        Vt[byte >> 1] = vbuf[i];
      }
    }
    f32x4 sc[4];
#pragma unroll
    for (int n = 0; n < 4; ++n) {
      f32x4 z = {};
      const ushort* kp = qkv + (brow + kt * 64 + n * 16 + fr) * 2304 + 768 + h * 64 + fc * 8;
      bf16x8 k0 = *(const bf16x8*)kp;
      bf16x8 k1 = *(const bf16x8*)(kp + 32);
      z = __builtin_amdgcn_mfma_f32_16x16x32_bf16(qf[0], k0, z, 0, 0, 0);
      z = __builtin_amdgcn_mfma_f32_16x16x32_bf16(qf[1], k1, z, 0, 0, 0);
      sc[n] = z;
    }
    float part[4] = {0.f, 0.f, 0.f, 0.f};
#pragma unroll
    for (int n = 0; n < 4; ++n) {
      int j = kt * 64 + n * 16 + fr;
      bool jv = j < NTOK;
#pragma unroll
      for (int rr = 0; rr < 4; ++rr) {
        float e = jv ? __expf(sc[n][rr] * 0.125f) : 0.f;
        part[rr] += e;
        int row = fc * 4 + rr, col = n * 16 + fr;
        int byte = row * 128 + (((col >> 3) ^ (row & 7)) << 4) + (col & 7) * 2;
        Pl[w * 1024 + (byte >> 1)] = f2b(e);
      }
    }
#pragma unroll
    for (int rr = 0; rr < 4; ++rr) {
      float p = part[rr];
      p += __shfl_xor(p, 1); p += __shfl_xor(p, 2);
      p += __shfl_xor(p, 4); p += __shfl_xor(p, 8);
      rs[rr] += p;
    }
    __syncthreads();
#pragma unroll
    for (int ks = 0; ks < 2; ++ks) {
      int prow = fr;
      int pbyte = prow * 128 + (((ks * 4 + fc) ^ (prow & 7)) << 4);
      bf16x8 pf = *(const bf16x8*)(Pl + w * 1024 + (pbyte >> 1));
#pragma unroll
      for (int n = 0; n < 4; ++n) {
        int d = n * 16 + fr;
        int vb = d * 128 + (((ks * 4 + fc) ^ (d & 7)) << 4);
        bf16x8 vf = *(const bf16x8*)(Vt + (vb >> 1));
        oc[n] = __builtin_amdgcn_mfma_f32_16x16x32_bf16(pf, vf, oc[n], 0, 0, 0);
      }
    }
  }
#pragma unroll
  for (int n = 0; n < 4; ++n) {
#pragma unroll
    for (int rr = 0; rr < 4; ++rr) {
      int qq = q0 + fc * 4 + rr;
      if (qq < NTOK) {
        float v = oc[n][rr] / (rs[rr] + 1e-8f);
        aout[(brow + qq) * 768 + h * 64 + n * 16 + fr] = f2b(v);
      }
    }
  }
}

// ---------------- host launch ----------------
extern "C" void kernel_launch(void* const* d_in, const int* in_sizes, int n_in,
                              void* d_out, int out_size, void* d_ws, size_t ws_size,
                              hipStream_t stream) {
  const float* img       = (const float*)d_in[0];
  const float* p_ln1_g   = (const float*)d_in[1];
  const float* p_ln1_b   = (const float*)d_in[2];
  const float* patch_w   = (const float*)d_in[3];
  const float* patch_b   = (const float*)d_in[4];
  const float* p_ln2_g   = (const float*)d_in[5];
  const float* p_ln2_b   = (const float*)d_in[6];
  const float* pos_emb   = (const float*)d_in[7];
  const float* cls_tok   = (const float*)d_in[8];
  const float* attn_ln_g = (const float*)d_in[9];
  const float* attn_ln_b = (const float*)d_in[10];
  const float* w_qkv     = (const float*)d_in[11];
  const float* w_out     = (const float*)d_in[12];
  const float* b_out     = (const float*)d_in[13];
  const float* ff_ln_g   = (const float*)d_in[14];
  const float* ff_ln_b   = (const float*)d_in[15];
  const float* ff_w1     = (const float*)d_in[16];
  const float* ff_b1     = (const float*)d_in[17];
  const float* ff_w2     = (const float*)d_in[18];
  const float* ff_b2     = (const float*)d_in[19];
  const float* fin_ln_g  = (const float*)d_in[20];
  const float* fin_ln_b  = (const float*)d_in[21];
  const float* head_w    = (const float*)d_in[22];
  const float* head_b    = (const float*)d_in[23];
  float* out = (float*)d_out;

  // ---- workspace carve ----
  char* p = (char*)d_ws;
  auto alloc = [&](size_t bytes) { char* r = p; p += (bytes + 255) & ~(size_t)255; return r; };
  ushort* x      = (ushort*)alloc((size_t)ROWS_PAD * 768 * 2);    // bf16 residual stream
  ushort* xnb    = (ushort*)alloc((size_t)ROWS_PAD * 768 * 2);
  ushort* qkvb   = (ushort*)alloc((size_t)ROWS_PAD * 2304 * 2);
  ushort* aoutb  = (ushort*)alloc((size_t)ROWS_PAD * 768 * 2);
  ushort* pwt    = (ushort*)alloc((size_t)768 * 768 * 2);
  ushort* hwt    = (ushort*)alloc((size_t)1024 * 768 * 2);
  ushort* xclsb  = (ushort*)alloc((size_t)128 * 768 * 2);
  ushort* hidb   = qkvb;                 // [ROWS_PAD][3072] aliases qkvb+aoutb
  ushort* xpb    = xnb;                  // patch LN1 out (12544 rows)
  float*  xe     = (float*)qkvb;         // patch GEMM out fp32 (pre-loop only)

  const size_t SQ = (size_t)2304 * 768, SO = (size_t)768 * 768, S1 = (size_t)MFF * 768;
  size_t used = (size_t)(p - (char*)d_ws);
  bool oneshot = (used + 12 * (SQ + SO + 2 * S1) * 2 + 4096) <= ws_size;
  int nw = oneshot ? 12 : 1;
  ushort* wtq = (ushort*)alloc(nw * SQ * 2);
  ushort* wto = (ushort*)alloc(nw * SO * 2);
  ushort* wt1 = (ushort*)alloc(nw * S1 * 2);
  ushort* wt2 = (ushort*)alloc(nw * S1 * 2);

  dim3 blk(256), tblk(32, 8);

  // ---- patch embedding ----
  transpose_cast<<<dim3(24, 24), tblk, 0, stream>>>(patch_w, pwt, 768, 768);
  transpose_cast<<<dim3(32, 24), tblk, 0, stream>>>(head_w, hwt, 768, 1000);
  if (oneshot)
    transpose_all<<<12 * 1728, blk, 0, stream>>>(w_qkv, w_out, ff_w1, ff_w2,
                                                 wtq, wto, wt1, wt2);
  patch_ln1<<<PROWS, blk, 0, stream>>>(img, p_ln1_g, p_ln1_b, xpb);
  gemm_v6<0, 0, 0><<<dim3(6, 98), blk, 0, stream>>>(xpb, pwt, patch_b, nullptr, xe,
                                                    PROWS, 768, 768);
  ln2_pos<<<PROWS, blk, 0, stream>>>(xe, p_ln2_g, p_ln2_b, pos_emb, x);
  cls_init<<<B_, blk, 0, stream>>>(cls_tok, pos_emb, x);

  for (int l = 0; l < NL; ++l) {
    ushort* tq = wtq + (oneshot ? (size_t)l * SQ : 0);
    ushort* to = wto + (oneshot ? (size_t)l * SO : 0);
    ushort* t1 = wt1 + (oneshot ? (size_t)l * S1 : 0);
    ushort* t2 = wt2 + (oneshot ? (size_t)l * S1 : 0);
    if (!oneshot)
      transpose4<<<1728, blk, 0, stream>>>(w_qkv + (size_t)l * 768 * 2304,
                                           w_out + (size_t)l * 768 * 768,
                                           ff_w1 + (size_t)l * 768 * MFF,
                                           ff_w2 + (size_t)l * MFF * 768,
                                           tq, to, t1, t2);

    ln_rows4<<<ROWS / 4, blk, 0, stream>>>(x, 768, attn_ln_g + (size_t)l * 768,
                                           attn_ln_b + (size_t)l * 768, xnb);
    gemm_v6<0, 0, 1><<<dim3(18, 99), blk, 0, stream>>>(xnb, tq, nullptr, nullptr, qkvb,
                                                       ROWS, 2304, 768);
    attn_mfma<<<B_ * NH * 4, blk, 0, stream>>>(qkvb, aoutb);
    gemm_v6<0, 1, 1><<<dim3(6, 99), blk, 0, stream>>>(aoutb, to, b_out + (size_t)l * 768,
                                                      x, x, ROWS, 768, 768);
    ln_rows4<<<ROWS / 4, blk, 0, stream>>>(x, 768, ff_ln_g + (size_t)l * 768,
                                           ff_ln_b + (size_t)l * 768, xnb);
    gemm_v6<1, 0, 1><<<dim3(24, 99), blk, 0, stream>>>(xnb, t1, ff_b1 + (size_t)l * MFF,
                                                       nullptr, hidb, ROWS, MFF, 768);
    gemm_v6<0, 1, 1><<<dim3(6, 99), blk, 0, stream>>>(hidb, t2, ff_b2 + (size_t)l * 768,
                                                      x, x, ROWS, 768, MFF);
  }

  // ---- final LN (cls rows) + head ----
  ln_rows4<<<B_ / 4, blk, 0, stream>>>(x, (long)NTOK * 768, fin_ln_g, fin_ln_b, xclsb);
  gemm_bt<0, 0, 0><<<dim3(8, 1), blk, 0, stream>>>(xclsb, hwt, head_b, nullptr, out,
                                                   B_, NCLS, 768);
}

// Round 18
// 4037.822 us; speedup vs baseline: 1.0924x; 1.0301x over previous
//
#include <hip/hip_runtime.h>
#include <hip/hip_bf16.h>
#include <math.h>

// ---- problem constants ----
#define B_     64
#define NTOK   197
#define NPATCH 196
#define D768   768
#define NL     12
#define NH     12
#define MFF    3072
#define NCLS   1000
#define ROWS   (B_ * NTOK)      // 12608
#define PROWS  (B_ * NPATCH)    // 12544
#define ROWS_PAD 12672          // 99 * 128

typedef unsigned short ushort;
typedef __bf16 bf16x8 __attribute__((ext_vector_type(8)));
typedef float  f32x4  __attribute__((ext_vector_type(4)));
typedef unsigned short u16x4 __attribute__((ext_vector_type(4)));
typedef unsigned short u16x2 __attribute__((ext_vector_type(2)));

__device__ __forceinline__ ushort f2b(float f) {
  __hip_bfloat16 h = __float2bfloat16(f);
  return *reinterpret_cast<ushort*>(&h);
}
__device__ __forceinline__ float b2f(ushort u) {
  unsigned int v = ((unsigned int)u) << 16;
  float f;
  __builtin_memcpy(&f, &v, 4);
  return f;
}

__device__ __forceinline__ void gload16(const ushort* g, ushort* lds) {
  __builtin_amdgcn_global_load_lds((const __attribute__((address_space(1))) void*)g,
                                   (__attribute__((address_space(3))) void*)lds, 16, 0, 0);
}

// tanh-form GELU via exp (max err ~1e-3, < bf16 quantization at those magnitudes)
__device__ __forceinline__ float gelu_f(float v) {
  float t = v * fmaf(0.0713548162726f, v * v, 1.5957691216f);
  return v / (1.0f + __expf(-t));
}

// ---------------- block-wide mean/rstd over 768 elems (256 threads) ----------------
__device__ __forceinline__ void block_mean_rstd(float s, float sq, float& mean, float& rstd) {
#pragma unroll
  for (int off = 32; off; off >>= 1) { s += __shfl_xor(s, off); sq += __shfl_xor(sq, off); }
  __shared__ float ss[4], ssq[4];
  int w = threadIdx.x >> 6;
  if ((threadIdx.x & 63) == 0) { ss[w] = s; ssq[w] = sq; }
  __syncthreads();
  s  = ss[0] + ss[1] + ss[2] + ss[3];
  sq = ssq[0] + ssq[1] + ssq[2] + ssq[3];
  mean = s * (1.0f / 768.0f);
  float var = sq * (1.0f / 768.0f) - mean * mean;
  rstd = rsqrtf(var + 1e-5f);
}

// ---------------- LN, wave-per-row: 4 rows/block, 12 bf16/lane, shfl-only reduce ----------------
__global__ __launch_bounds__(256) void ln_rows4(const ushort* __restrict__ in, long in_stride,
                                                const float* __restrict__ g,
                                                const float* __restrict__ bta,
                                                ushort* __restrict__ out) {
  const int w = threadIdx.x >> 6, l = threadIdx.x & 63;
  const size_t row = (size_t)blockIdx.x * 4 + w;
  const ushort* xr = in + row * in_stride;
  u16x4 xv[3];
  xv[0] = *(const u16x4*)(xr + l * 4);
  xv[1] = *(const u16x4*)(xr + 256 + l * 4);
  xv[2] = *(const u16x4*)(xr + 512 + l * 4);
  float v[12];
  float s = 0.f, sq = 0.f;
#pragma unroll
  for (int i = 0; i < 3; ++i)
#pragma unroll
    for (int j = 0; j < 4; ++j) {
      float f = b2f(xv[i][j]);
      v[i * 4 + j] = f;
      s += f; sq += f * f;
    }
#pragma unroll
  for (int off = 32; off; off >>= 1) { s += __shfl_xor(s, off); sq += __shfl_xor(sq, off); }
  float mean = s * (1.0f / 768.0f);
  float rstd = rsqrtf(sq * (1.0f / 768.0f) - mean * mean + 1e-5f);
  ushort* o = out + row * 768;
#pragma unroll
  for (int i = 0; i < 3; ++i) {
    int base = i * 256 + l * 4;
    f32x4 gv = *(const f32x4*)(g + base);
    f32x4 bv = *(const f32x4*)(bta + base);
    u16x4 ov = { f2b((v[i*4+0] - mean) * rstd * gv[0] + bv[0]),
                 f2b((v[i*4+1] - mean) * rstd * gv[1] + bv[1]),
                 f2b((v[i*4+2] - mean) * rstd * gv[2] + bv[2]),
                 f2b((v[i*4+3] - mean) * rstd * gv[3] + bv[3]) };
    *(u16x4*)(o + base) = ov;
  }
}

// ---------------- patch extraction + LN1 (bf16 out), coalesced img loads ----------------
// lane t <-> pixel (p1 = t>>4, p2 = t&15); c in registers. Feature k = t*3 + c.
__global__ __launch_bounds__(256) void patch_ln1(const float* __restrict__ img,
                                                 const float* __restrict__ g,
                                                 const float* __restrict__ bta,
                                                 ushort* __restrict__ xp) {
  int pidx = blockIdx.x;                 // b*196 + ph*14 + pw
  int b = pidx / NPATCH, hw = pidx % NPATCH;
  int ph = hw / 14, pw = hw % 14;
  int t = threadIdx.x;
  int p1 = t >> 4, p2 = t & 15;
  float v[3];
#pragma unroll
  for (int c = 0; c < 3; ++c)
    v[c] = img[(((size_t)b * 3 + c) * 224 + ph * 16 + p1) * 224 + pw * 16 + p2];
  float mean, rstd;
  block_mean_rstd(v[0] + v[1] + v[2], v[0] * v[0] + v[1] * v[1] + v[2] * v[2], mean, rstd);
  ushort* o = xp + (size_t)pidx * 768;
#pragma unroll
  for (int c = 0; c < 3; ++c) {
    int k = t * 3 + c;
    o[k] = f2b((v[c] - mean) * rstd * g[k] + bta[k]);
  }
}

// ---------------- LN2 + pos_emb, scatter into x (bf16) at token 1+i ----------------
__global__ __launch_bounds__(256) void ln2_pos(const float* __restrict__ xe,
                                               const float* __restrict__ g,
                                               const float* __restrict__ bta,
                                               const float* __restrict__ pos,
                                               ushort* __restrict__ x) {
  int pidx = blockIdx.x;
  int b = pidx / NPATCH, i = pidx % NPATCH;
  const float* xr = xe + (size_t)pidx * 768;
  int t = threadIdx.x;
  float v0 = xr[t], v1 = xr[t + 256], v2 = xr[t + 512];
  float mean, rstd;
  block_mean_rstd(v0 + v1 + v2, v0 * v0 + v1 * v1 + v2 * v2, mean, rstd);
  const float* p = pos + (size_t)(1 + i) * 768;
  ushort* o = x + ((size_t)b * NTOK + 1 + i) * 768;
  o[t]       = f2b((v0 - mean) * rstd * g[t]       + bta[t]       + p[t]);
  o[t + 256] = f2b((v1 - mean) * rstd * g[t + 256] + bta[t + 256] + p[t + 256]);
  o[t + 512] = f2b((v2 - mean) * rstd * g[t + 512] + bta[t + 512] + p[t + 512]);
}

// ---------------- cls token + pos_emb[0] (bf16 out) ----------------
__global__ __launch_bounds__(256) void cls_init(const float* __restrict__ cls_tok,
                                                const float* __restrict__ pos,
                                                ushort* __restrict__ x) {
  int b = blockIdx.x, t = threadIdx.x;
  ushort* o = x + (size_t)b * NTOK * 768;
#pragma unroll
  for (int u = 0; u < 3; ++u) { int k = t + u * 256; o[k] = f2b(cls_tok[k] + pos[k]); }
}

// ---------------- cast + transpose: W fp32 [K][N] -> Wt bf16 [N][K] (bounds-checked) ----------------
__global__ __launch_bounds__(256) void transpose_cast(const float* __restrict__ W,
                                                      ushort* __restrict__ Wt,
                                                      int K, int N) {
  __shared__ float t[32][33];
  int n0 = blockIdx.x * 32, k0 = blockIdx.y * 32;
  int tx = threadIdx.x, ty = threadIdx.y;   // 32 x 8
#pragma unroll
  for (int u = 0; u < 32; u += 8) {
    int n = n0 + tx;
    t[ty + u][tx] = (n < N) ? W[(size_t)(k0 + ty + u) * N + n] : 0.f;
  }
  __syncthreads();
#pragma unroll
  for (int u = 0; u < 32; u += 8) {
    int n = n0 + ty + u;
    if (n < N) Wt[(size_t)n * K + k0 + tx] = f2b(t[tx][ty + u]);
  }
}

// ---------------- 64x64 vectorized transpose (dims % 64 == 0), flat 256 thr ----------------
__device__ __forceinline__ void transpose_layer64(int bid,
                                                  const float* wq, const float* wo,
                                                  const float* w1, const float* w2,
                                                  ushort* tq, ushort* to,
                                                  ushort* t1, ushort* t2) {
  const float* W; ushort* Wt; int K, N, xt;
  if (bid < 432)       {             W = wq; Wt = tq; K = 768;  N = 2304; xt = 36; }
  else if (bid < 576)  { bid -= 432; W = wo; Wt = to; K = 768;  N = 768;  xt = 12; }
  else if (bid < 1152) { bid -= 576; W = w1; Wt = t1; K = 768;  N = 3072; xt = 48; }
  else                 { bid -= 1152; W = w2; Wt = t2; K = 3072; N = 768; xt = 12; }
  int n0 = (bid % xt) * 64, k0 = (bid / xt) * 64;
  __shared__ float t[64][65];
  int id = threadIdx.x;
  int tx = id & 15, ty = id >> 4;           // load: 16 lanes x 16 rows per pass
#pragma unroll
  for (int u = 0; u < 4; ++u) {
    int k = ty + 16 * u;
    f32x4 v = *(const f32x4*)(W + (size_t)(k0 + k) * N + n0 + tx * 4);
    t[k][tx * 4 + 0] = v[0]; t[k][tx * 4 + 1] = v[1];
    t[k][tx * 4 + 2] = v[2]; t[k][tx * 4 + 3] = v[3];
  }
  __syncthreads();
  int wx = id & 31, wy = id >> 5;           // write: 32 lanes x 8 n-rows per pass
#pragma unroll
  for (int u = 0; u < 8; ++u) {
    int n = wy + 8 * u;
    u16x2 o = { f2b(t[wx * 2][n]), f2b(t[wx * 2 + 1][n]) };
    *(u16x2*)(Wt + (size_t)(n0 + n) * K + k0 + wx * 2) = o;
  }
}

__global__ __launch_bounds__(256) void transpose4(const float* __restrict__ wq,
                                                  const float* __restrict__ wo,
                                                  const float* __restrict__ w1,
                                                  const float* __restrict__ w2,
                                                  ushort* __restrict__ tq,
                                                  ushort* __restrict__ to,
                                                  ushort* __restrict__ t1,
                                                  ushort* __restrict__ t2) {
  transpose_layer64(blockIdx.x, wq, wo, w1, w2, tq, to, t1, t2);
}

__global__ __launch_bounds__(256) void transpose_all(const float* __restrict__ wq,
                                                     const float* __restrict__ wo,
                                                     const float* __restrict__ w1,
                                                     const float* __restrict__ w2,
                                                     ushort* __restrict__ tq,
                                                     ushort* __restrict__ to,
                                                     ushort* __restrict__ t1,
                                                     ushort* __restrict__ t2) {
  int l = blockIdx.x / 1728, bid = blockIdx.x % 1728;
  transpose_layer64(bid,
                    wq + (size_t)l * 768 * 2304, wo + (size_t)l * 768 * 768,
                    w1 + (size_t)l * 768 * MFF,  w2 + (size_t)l * MFF * 768,
                    tq + (size_t)l * 2304 * 768, to + (size_t)l * 768 * 768,
                    t1 + (size_t)l * MFF * 768,  t2 + (size_t)l * 768 * MFF);
}

// ================= bf16 MFMA GEMM v6: 2-buf counted-vmcnt (128x128) =================
template<int EP, int RESID, int OBF>
__global__ __launch_bounds__(256, 4) void gemm_v6(const ushort* __restrict__ A,
                                                  const ushort* __restrict__ Bt,
                                                  const float* __restrict__ bias,
                                                  const void* __restrict__ resid,
                                                  void* __restrict__ Cv,
                                                  int M, int N, int K) {
  __shared__ ushort smem[2 * 8192];

  const int tid = threadIdx.x;
  const int w = tid >> 6, l = tid & 63;
  const int fr = l & 15, fc = l >> 4;

  const int ntx = gridDim.x;
  const int nwg = ntx * gridDim.y;
  const int orig = blockIdx.y * ntx + blockIdx.x;
  const int q = nwg >> 3, r = nwg & 7, xcd = orig & 7, idx = orig >> 3;
  const int wg = (xcd < r ? xcd * (q + 1) : r * (q + 1) + (xcd - r) * q) + idx;
  const int row0 = (wg / ntx) * 128, col0 = (wg % ntx) * 128;

  const int wr = (w >> 1) * 64, wc = (w & 1) * 64;

  const int srow = tid >> 2;
  const int sg = (tid & 3) ^ ((srow >> 1) & 3);
  const ushort* pA0 = A  + (size_t)(row0 + srow) * K + sg * 8;
  const ushort* pA1 = A  + (size_t)(row0 + 64 + srow) * K + sg * 8;
  const ushort* pB0 = Bt + (size_t)(col0 + srow) * K + sg * 8;
  const ushort* pB1 = Bt + (size_t)(col0 + 64 + srow) * K + sg * 8;

  auto stage = [&](int t_, ushort* dst) {
    const int k0 = t_ * 32;
    gload16(pA0 + k0, dst + tid * 8);
    gload16(pA1 + k0, dst + (tid + 256) * 8);
    gload16(pB0 + k0, dst + 4096 + tid * 8);
    gload16(pB1 + k0, dst + 4096 + (tid + 256) * 8);
  };

  int idxA[4], idxB[4];
#pragma unroll
  for (int m = 0; m < 4; ++m) {
    int rA = wr + m * 16 + fr;
    idxA[m] = rA * 32 + ((fc ^ ((rA >> 1) & 3)) << 3);
  }
#pragma unroll
  for (int n = 0; n < 4; ++n) {
    int rB = wc + n * 16 + fr;
    idxB[n] = rB * 32 + ((fc ^ ((rB >> 1) & 3)) << 3);
  }

  f32x4 acc[4][4] = {};

  auto compute = [&](const ushort* As) {
    const ushort* Bs = As + 4096;
    bf16x8 a_[4], b_[4];
#pragma unroll
    for (int m = 0; m < 4; ++m) a_[m] = *(const bf16x8*)(As + idxA[m]);
#pragma unroll
    for (int n = 0; n < 4; ++n) b_[n] = *(const bf16x8*)(Bs + idxB[n]);
#pragma unroll
    for (int m = 0; m < 4; ++m)
#pragma unroll
      for (int n = 0; n < 4; ++n)
        acc[m][n] = __builtin_amdgcn_mfma_f32_16x16x32_bf16(b_[n], a_[m], acc[m][n], 0, 0, 0);
  };

#define VM4() asm volatile("s_waitcnt vmcnt(4)" ::: "memory")
#define VM0() asm volatile("s_waitcnt vmcnt(0)" ::: "memory")

  const int NT = K >> 5;

  stage(0, smem);
  for (int t = 0; t < NT; t += 2) {
    if (t + 1 < NT) { stage(t + 1, smem + 8192); VM4(); } else VM0();
    __builtin_amdgcn_s_barrier();
    compute(smem);
    __builtin_amdgcn_s_barrier();
    if (t + 1 < NT) {
      if (t + 2 < NT) { stage(t + 2, smem); VM4(); } else VM0();
      __builtin_amdgcn_s_barrier();
      compute(smem + 8192);
      __builtin_amdgcn_s_barrier();
    }
  }
#undef VM4
#undef VM0

  if (!OBF) {
    float* Cf = (float*)Cv;
#pragma unroll
    for (int m = 0; m < 4; ++m) {
      int row = row0 + wr + m * 16 + fr;
      if (row >= M) continue;
#pragma unroll
      for (int n = 0; n < 4; ++n) {
        int col = col0 + wc + n * 16 + fc * 4;
        f32x4 v = acc[m][n];
        if (bias) v += *(const f32x4*)(bias + col);
        if (EP) {
#pragma unroll
          for (int rr = 0; rr < 4; ++rr) v[rr] = gelu_f(v[rr]);
        }
        if (RESID) v += *(const f32x4*)((const float*)resid + (size_t)row * N + col);
        *(f32x4*)(Cf + (size_t)row * N + col) = v;
      }
    }
  } else {
    __syncthreads();
    ushort* Cw = smem + w * 4096;
#pragma unroll
    for (int m = 0; m < 4; ++m) {
      int rl = m * 16 + fr;
      int row = row0 + wr + rl;
#pragma unroll
      for (int n = 0; n < 4; ++n) {
        int col = col0 + wc + n * 16 + fc * 4;
        f32x4 v = acc[m][n];
        if (bias) v += *(const f32x4*)(bias + col);
        if (EP) {
#pragma unroll
          for (int rr = 0; rr < 4; ++rr) v[rr] = gelu_f(v[rr]);
        }
        if (RESID) {
          u16x4 rv = *(const u16x4*)((const ushort*)resid + (size_t)row * N + col);
#pragma unroll
          for (int rr = 0; rr < 4; ++rr) v[rr] += b2f(rv[rr]);
        }
        u16x4 pk = { f2b(v[0]), f2b(v[1]), f2b(v[2]), f2b(v[3]) };
        int s = (n * 4 + fc) ^ (rl & 7);
        *(u16x4*)(Cw + rl * 64 + s * 4) = pk;
      }
    }
    ushort* Cb = (ushort*)Cv;
#pragma unroll
    for (int pp = 0; pp < 16; ++pp) {
      int rl = pp * 4 + (l >> 4);
      int cs = l & 15;
      u16x4 pk = *(const u16x4*)(Cw + rl * 64 + ((cs ^ (rl & 7)) * 4));
      int row = row0 + wr + rl;
      if (row < M) *(u16x4*)(Cb + (size_t)row * N + col0 + wc + cs * 4) = pk;
    }
  }
}

// ---------------- 128x128 bf16 MFMA GEMM (head only, N-bounds-safe) ----------------
template<int EP, int RESID, int OBF>
__global__ __launch_bounds__(256) void gemm_bt(const ushort* __restrict__ A,
                                               const ushort* __restrict__ Bt,
                                               const float* __restrict__ bias,
                                               const float* __restrict__ resid,
                                               void* __restrict__ C,
                                               int M, int N, int K) {
  __shared__ ushort As[128 * 32];
  __shared__ ushort Bs[128 * 32];
  int tid = threadIdx.x;
  int w = tid >> 6, l = tid & 63;
  int fr = l & 15, fc = l >> 4;
  int row0 = blockIdx.y * 128, col0 = blockIdx.x * 128;
  int wr = (w >> 1) * 64, wc = (w & 1) * 64;

  int srow0 = w * 32 + (l >> 2);
  int srow1 = srow0 + 16;
  int sc0 = (((l & 3) ^ ((srow0 >> 1) & 3)) << 3);
  int sc1 = (((l & 3) ^ ((srow1 >> 1) & 3)) << 3);
  const ushort* ga0 = A  + (size_t)(row0 + srow0) * K + sc0;
  const ushort* ga1 = A  + (size_t)(row0 + srow1) * K + sc1;
  const ushort* gb0 = Bt + (size_t)(col0 + srow0) * K + sc0;
  const ushort* gb1 = Bt + (size_t)(col0 + srow1) * K + sc1;

  int idxA[4], idxB[4];
#pragma unroll
  for (int m = 0; m < 4; ++m) {
    int rA = wr + m * 16 + fr;
    idxA[m] = rA * 32 + ((fc ^ ((rA >> 1) & 3)) << 3);
  }
#pragma unroll
  for (int n = 0; n < 4; ++n) {
    int rB = wc + n * 16 + fr;
    idxB[n] = rB * 32 + ((fc ^ ((rB >> 1) & 3)) << 3);
  }

  f32x4 acc[4][4] = {};

  for (int k0 = 0; k0 < K; k0 += 32) {
    gload16(ga0 + k0, &As[w * 1024]);
    gload16(ga1 + k0, &As[w * 1024 + 512]);
    gload16(gb0 + k0, &Bs[w * 1024]);
    gload16(gb1 + k0, &Bs[w * 1024 + 512]);
    __syncthreads();
    bf16x8 af[4], bfr[4];
#pragma unroll
    for (int m = 0; m < 4; ++m) af[m] = *(const bf16x8*)(As + idxA[m]);
#pragma unroll
    for (int n = 0; n < 4; ++n) bfr[n] = *(const bf16x8*)(Bs + idxB[n]);
#pragma unroll
    for (int m = 0; m < 4; ++m)
#pragma unroll
      for (int n = 0; n < 4; ++n)
        acc[m][n] = __builtin_amdgcn_mfma_f32_16x16x32_bf16(af[m], bfr[n], acc[m][n], 0, 0, 0);
    __syncthreads();
  }

#pragma unroll
  for (int n = 0; n < 4; ++n) {
    int col = col0 + wc + n * 16 + fr;
    if (col >= N) continue;
    float bv = bias ? bias[col] : 0.f;
#pragma unroll
    for (int m = 0; m < 4; ++m) {
#pragma unroll
      for (int rr = 0; rr < 4; ++rr) {
        int row = row0 + wr + m * 16 + fc * 4 + rr;
        if (row >= M) continue;
        float v = acc[m][n][rr] + bv;
        if (EP == 1) v = 0.5f * v * (1.0f + erff(v * 0.70710678118654752f));
        if (RESID) v += resid[(size_t)row * N + col];
        if (OBF) ((ushort*)C)[(size_t)row * N + col] = f2b(v);
        else     ((float*)C)[(size_t)row * N + col]  = v;
      }
    }
  }
}

// ---------------- MFMA flash attention: K staged in LDS, (b,h)-per-XCD grid ----------------
// grid remap (bijective, 3072 blocks): dispatched bid' = (bh&7) + 8*qt + 32*(bh>>3)
// so the 4 qt-blocks of one (b,h) share an XCD's L2 (round-robin assumption; perf-only).
// K tile staged via gload16 into [key][64] with slot' = slot ^ ((key>>1)&7)
// (3-bit XOR: 128B rows -> bank-group = slot, so 2-bit XOR would leave 4-way conflicts).
__global__ __launch_bounds__(256) void attn_mfma(const ushort* __restrict__ qkv,
                                                 ushort* __restrict__ aout) {
  int bidp = blockIdx.x;
  int bh = (bidp & 7) | ((bidp >> 5) << 3);
  int qt = (bidp >> 3) & 3;
  int h  = bh % NH;
  int b  = bh / NH;
  int tid = threadIdx.x, w = tid >> 6, l = tid & 63;
  int fr = l & 15, fc = l >> 4;

  __shared__ ushort Kt[64 * 64];        // [key][64], slot'^=(key>>1)&7
  __shared__ ushort Vt[64 * 64];        // swizzled V^T tile [d][key]
  __shared__ ushort Pl[4 * 16 * 64];    // per-wave P [qrow][key], swizzled

  const size_t brow = (size_t)b * NTOK;
  int q0 = qt * 64 + w * 16;

  // K staging coords: chunk c = tid, tid+256; key = c>>3, slot = c&7,
  // src slot g = slot ^ ((key>>1)&7). (key+32)>>1 changes by 16 -> &7 unchanged.
  const int skey = tid >> 3;
  const int sgk = (tid & 7) ^ ((skey >> 1) & 7);
  const ushort* pK0 = qkv + (brow + skey) * 2304 + 768 + h * 64 + sgk * 8;
  const ushort* pK1 = qkv + (brow + 32 + skey) * 2304 + 768 + h * 64 + sgk * 8;

  bf16x8 qf[2];
  {
    const ushort* qp = qkv + (brow + q0 + fr) * 2304 + h * 64 + fc * 8;
    qf[0] = *(const bf16x8*)qp;
    qf[1] = *(const bf16x8*)(qp + 32);
  }
  float rs[4] = {0.f, 0.f, 0.f, 0.f};
  f32x4 oc[4] = {};

  for (int kt = 0; kt < 4; ++kt) {
    __syncthreads();                      // prev tile's Kt/Vt reads complete
    // stage K tile (j >= NTOK rows contain garbage; their scores are masked below)
    {
      const size_t koff = (size_t)kt * 64 * 2304;
      gload16(pK0 + koff, Kt + tid * 8);
      gload16(pK1 + koff, Kt + (tid + 256) * 8);
    }
    // stage V^T tile (zero-filled beyond 197 keys)
    {
      int key = tid >> 2, d0 = (tid & 3) * 16;
      int j = kt * 64 + key;
      bool valid = j < NTOK;
      const ushort* vp = qkv + (brow + j) * 2304 + 1536 + h * 64 + d0;
      ushort vbuf[16];
      if (valid) {
        *(bf16x8*)(vbuf)     = *(const bf16x8*)vp;
        *(bf16x8*)(vbuf + 8) = *(const bf16x8*)(vp + 8);
      } else {
#pragma unroll
        for (int i = 0; i < 16; ++i) vbuf[i] = 0;
      }
#pragma unroll
      for (int i = 0; i < 16; ++i) {
        int d = d0 + i;
        int byte = d * 128 + ((((key >> 3)) ^ (d & 7)) << 4) + (key & 7) * 2;
        Vt[byte >> 1] = vbuf[i];
      }
    }
    asm volatile("s_waitcnt vmcnt(0)" ::: "memory");   // K landed
    __syncthreads();                                   // Kt + Vt visible
    // S = Q K^T from LDS K
    f32x4 sc[4];
#pragma unroll
    for (int n = 0; n < 4; ++n) {
      int row = n * 16 + fr;
      int sw = (row >> 1) & 7;
      const ushort* kr = Kt + row * 64;
      bf16x8 k0 = *(const bf16x8*)(kr + ((fc ^ sw) << 3));
      bf16x8 k1 = *(const bf16x8*)(kr + (((fc + 4) ^ sw) << 3));
      f32x4 z = {};
      z = __builtin_amdgcn_mfma_f32_16x16x32_bf16(qf[0], k0, z, 0, 0, 0);
      z = __builtin_amdgcn_mfma_f32_16x16x32_bf16(qf[1], k1, z, 0, 0, 0);
      sc[n] = z;
    }
    float part[4] = {0.f, 0.f, 0.f, 0.f};
#pragma unroll
    for (int n = 0; n < 4; ++n) {
      int j = kt * 64 + n * 16 + fr;
      bool jv = j < NTOK;
#pragma unroll
      for (int rr = 0; rr < 4; ++rr) {
        float e = jv ? __expf(sc[n][rr] * 0.125f) : 0.f;
        part[rr] += e;
        int row = fc * 4 + rr, col = n * 16 + fr;
        int byte = row * 128 + (((col >> 3) ^ (row & 7)) << 4) + (col & 7) * 2;
        Pl[w * 1024 + (byte >> 1)] = f2b(e);
      }
    }
#pragma unroll
    for (int rr = 0; rr < 4; ++rr) {
      float p = part[rr];
      p += __shfl_xor(p, 1); p += __shfl_xor(p, 2);
      p += __shfl_xor(p, 4); p += __shfl_xor(p, 8);
      rs[rr] += p;
    }
    __syncthreads();
#pragma unroll
    for (int ks = 0; ks < 2; ++ks) {
      int prow = fr;
      int pbyte = prow * 128 + (((ks * 4 + fc) ^ (prow & 7)) << 4);
      bf16x8 pf = *(const bf16x8*)(Pl + w * 1024 + (pbyte >> 1));
#pragma unroll
      for (int n = 0; n < 4; ++n) {
        int d = n * 16 + fr;
        int vb = d * 128 + (((ks * 4 + fc) ^ (d & 7)) << 4);
        bf16x8 vf = *(const bf16x8*)(Vt + (vb >> 1));
        oc[n] = __builtin_amdgcn_mfma_f32_16x16x32_bf16(pf, vf, oc[n], 0, 0, 0);
      }
    }
  }
#pragma unroll
  for (int n = 0; n < 4; ++n) {
#pragma unroll
    for (int rr = 0; rr < 4; ++rr) {
      int qq = q0 + fc * 4 + rr;
      if (qq < NTOK) {
        float v = oc[n][rr] / (rs[rr] + 1e-8f);
        aout[(brow + qq) * 768 + h * 64 + n * 16 + fr] = f2b(v);
      }
    }
  }
}

// ---------------- host launch ----------------
extern "C" void kernel_launch(void* const* d_in, const int* in_sizes, int n_in,
                              void* d_out, int out_size, void* d_ws, size_t ws_size,
                              hipStream_t stream) {
  const float* img       = (const float*)d_in[0];
  const float* p_ln1_g   = (const float*)d_in[1];
  const float* p_ln1_b   = (const float*)d_in[2];
  const float* patch_w   = (const float*)d_in[3];
  const float* patch_b   = (const float*)d_in[4];
  const float* p_ln2_g   = (const float*)d_in[5];
  const float* p_ln2_b   = (const float*)d_in[6];
  const float* pos_emb   = (const float*)d_in[7];
  const float* cls_tok   = (const float*)d_in[8];
  const float* attn_ln_g = (const float*)d_in[9];
  const float* attn_ln_b = (const float*)d_in[10];
  const float* w_qkv     = (const float*)d_in[11];
  const float* w_out     = (const float*)d_in[12];
  const float* b_out     = (const float*)d_in[13];
  const float* ff_ln_g   = (const float*)d_in[14];
  const float* ff_ln_b   = (const float*)d_in[15];
  const float* ff_w1     = (const float*)d_in[16];
  const float* ff_b1     = (const float*)d_in[17];
  const float* ff_w2     = (const float*)d_in[18];
  const float* ff_b2     = (const float*)d_in[19];
  const float* fin_ln_g  = (const float*)d_in[20];
  const float* fin_ln_b  = (const float*)d_in[21];
  const float* head_w    = (const float*)d_in[22];
  const float* head_b    = (const float*)d_in[23];
  float* out = (float*)d_out;

  // ---- workspace carve ----
  char* p = (char*)d_ws;
  auto alloc = [&](size_t bytes) { char* r = p; p += (bytes + 255) & ~(size_t)255; return r; };
  ushort* x      = (ushort*)alloc((size_t)ROWS_PAD * 768 * 2);    // bf16 residual stream
  ushort* xnb    = (ushort*)alloc((size_t)ROWS_PAD * 768 * 2);
  ushort* qkvb   = (ushort*)alloc((size_t)ROWS_PAD * 2304 * 2);
  ushort* aoutb  = (ushort*)alloc((size_t)ROWS_PAD * 768 * 2);
  ushort* pwt    = (ushort*)alloc((size_t)768 * 768 * 2);
  ushort* hwt    = (ushort*)alloc((size_t)1024 * 768 * 2);
  ushort* xclsb  = (ushort*)alloc((size_t)128 * 768 * 2);
  ushort* hidb   = qkvb;                 // [ROWS_PAD][3072] aliases qkvb+aoutb
  ushort* xpb    = xnb;                  // patch LN1 out (12544 rows)
  float*  xe     = (float*)qkvb;         // patch GEMM out fp32 (pre-loop only)

  const size_t SQ = (size_t)2304 * 768, SO = (size_t)768 * 768, S1 = (size_t)MFF * 768;
  size_t used = (size_t)(p - (char*)d_ws);
  bool oneshot = (used + 12 * (SQ + SO + 2 * S1) * 2 + 4096) <= ws_size;
  int nw = oneshot ? 12 : 1;
  ushort* wtq = (ushort*)alloc(nw * SQ * 2);
  ushort* wto = (ushort*)alloc(nw * SO * 2);
  ushort* wt1 = (ushort*)alloc(nw * S1 * 2);
  ushort* wt2 = (ushort*)alloc(nw * S1 * 2);

  dim3 blk(256), tblk(32, 8);

  // ---- patch embedding ----
  transpose_cast<<<dim3(24, 24), tblk, 0, stream>>>(patch_w, pwt, 768, 768);
  transpose_cast<<<dim3(32, 24), tblk, 0, stream>>>(head_w, hwt, 768, 1000);
  if (oneshot)
    transpose_all<<<12 * 1728, blk, 0, stream>>>(w_qkv, w_out, ff_w1, ff_w2,
                                                 wtq, wto, wt1, wt2);
  patch_ln1<<<PROWS, blk, 0, stream>>>(img, p_ln1_g, p_ln1_b, xpb);
  gemm_v6<0, 0, 0><<<dim3(6, 98), blk, 0, stream>>>(xpb, pwt, patch_b, nullptr, xe,
                                                    PROWS, 768, 768);
  ln2_pos<<<PROWS, blk, 0, stream>>>(xe, p_ln2_g, p_ln2_b, pos_emb, x);
  cls_init<<<B_, blk, 0, stream>>>(cls_tok, pos_emb, x);

  for (int l = 0; l < NL; ++l) {
    ushort* tq = wtq + (oneshot ? (size_t)l * SQ : 0);
    ushort* to = wto + (oneshot ? (size_t)l * SO : 0);
    ushort* t1 = wt1 + (oneshot ? (size_t)l * S1 : 0);
    ushort* t2 = wt2 + (oneshot ? (size_t)l * S1 : 0);
    if (!oneshot)
      transpose4<<<1728, blk, 0, stream>>>(w_qkv + (size_t)l * 768 * 2304,
                                           w_out + (size_t)l * 768 * 768,
                                           ff_w1 + (size_t)l * 768 * MFF,
                                           ff_w2 + (size_t)l * MFF * 768,
                                           tq, to, t1, t2);

    ln_rows4<<<ROWS / 4, blk, 0, stream>>>(x, 768, attn_ln_g + (size_t)l * 768,
                                           attn_ln_b + (size_t)l * 768, xnb);
    gemm_v6<0, 0, 1><<<dim3(18, 99), blk, 0, stream>>>(xnb, tq, nullptr, nullptr, qkvb,
                                                       ROWS, 2304, 768);
    attn_mfma<<<B_ * NH * 4, blk, 0, stream>>>(qkvb, aoutb);
    gemm_v6<0, 1, 1><<<dim3(6, 99), blk, 0, stream>>>(aoutb, to, b_out + (size_t)l * 768,
                                                      x, x, ROWS, 768, 768);
    ln_rows4<<<ROWS / 4, blk, 0, stream>>>(x, 768, ff_ln_g + (size_t)l * 768,
                                           ff_ln_b + (size_t)l * 768, xnb);
    gemm_v6<1, 0, 1><<<dim3(24, 99), blk, 0, stream>>>(xnb, t1, ff_b1 + (size_t)l * MFF,
                                                       nullptr, hidb, ROWS, MFF, 768);
    gemm_v6<0, 1, 1><<<dim3(6, 99), blk, 0, stream>>>(hidb, t2, ff_b2 + (size_t)l * 768,
                                                      x, x, ROWS, MFF == MFF ? 768 : 768, MFF);
  }

  // ---- final LN (cls rows) + head ----
  ln_rows4<<<B_ / 4, blk, 0, stream>>>(x, (long)NTOK * 768, fin_ln_g, fin_ln_b, xclsb);
  gemm_bt<0, 0, 0><<<dim3(8, 1), blk, 0, stream>>>(xclsb, hwt, head_b, nullptr, out,
                                                   B_, NCLS, 768);
}

// Round 19
// 4034.462 us; speedup vs baseline: 1.0933x; 1.0008x over previous
//
#include <hip/hip_runtime.h>
#include <hip/hip_bf16.h>
#include <math.h>

// ---- problem constants ----
#define B_     64
#define NTOK   197
#define NPATCH 196
#define D768   768
#define NL     12
#define NH     12
#define MFF    3072
#define NCLS   1000
#define ROWS   (B_ * NTOK)      // 12608
#define PROWS  (B_ * NPATCH)    // 12544
#define ROWS_PAD 12672          // 99 * 128

typedef unsigned short ushort;
typedef __bf16 bf16x8 __attribute__((ext_vector_type(8)));
typedef float  f32x4  __attribute__((ext_vector_type(4)));
typedef unsigned short u16x4 __attribute__((ext_vector_type(4)));

__device__ __forceinline__ ushort f2b(float f) {
  __hip_bfloat16 h = __float2bfloat16(f);
  return *reinterpret_cast<ushort*>(&h);
}
__device__ __forceinline__ float b2f(ushort u) {
  unsigned int v = ((unsigned int)u) << 16;
  float f;
  __builtin_memcpy(&f, &v, 4);
  return f;
}

__device__ __forceinline__ void gload16(const ushort* g, ushort* lds) {
  __builtin_amdgcn_global_load_lds((const __attribute__((address_space(1))) void*)g,
                                   (__attribute__((address_space(3))) void*)lds, 16, 0, 0);
}

// tanh-form GELU via exp (max err ~1e-3, < bf16 quantization at those magnitudes)
__device__ __forceinline__ float gelu_f(float v) {
  float t = v * fmaf(0.0713548162726f, v * v, 1.5957691216f);
  return v / (1.0f + __expf(-t));
}

// ---------------- block-wide mean/rstd over 768 elems (256 threads) ----------------
__device__ __forceinline__ void block_mean_rstd(float s, float sq, float& mean, float& rstd) {
#pragma unroll
  for (int off = 32; off; off >>= 1) { s += __shfl_xor(s, off); sq += __shfl_xor(sq, off); }
  __shared__ float ss[4], ssq[4];
  int w = threadIdx.x >> 6;
  if ((threadIdx.x & 63) == 0) { ss[w] = s; ssq[w] = sq; }
  __syncthreads();
  s  = ss[0] + ss[1] + ss[2] + ss[3];
  sq = ssq[0] + ssq[1] + ssq[2] + ssq[3];
  mean = s * (1.0f / 768.0f);
  float var = sq * (1.0f / 768.0f) - mean * mean;
  rstd = rsqrtf(var + 1e-5f);
}

// ---------------- LN, wave-per-row: 4 rows/block, 12 bf16/lane, shfl-only reduce ----------------
__global__ __launch_bounds__(256) void ln_rows4(const ushort* __restrict__ in, long in_stride,
                                                const float* __restrict__ g,
                                                const float* __restrict__ bta,
                                                ushort* __restrict__ out) {
  const int w = threadIdx.x >> 6, l = threadIdx.x & 63;
  const size_t row = (size_t)blockIdx.x * 4 + w;
  const ushort* xr = in + row * in_stride;
  u16x4 xv[3];
  xv[0] = *(const u16x4*)(xr + l * 4);
  xv[1] = *(const u16x4*)(xr + 256 + l * 4);
  xv[2] = *(const u16x4*)(xr + 512 + l * 4);
  float v[12];
  float s = 0.f, sq = 0.f;
#pragma unroll
  for (int i = 0; i < 3; ++i)
#pragma unroll
    for (int j = 0; j < 4; ++j) {
      float f = b2f(xv[i][j]);
      v[i * 4 + j] = f;
      s += f; sq += f * f;
    }
#pragma unroll
  for (int off = 32; off; off >>= 1) { s += __shfl_xor(s, off); sq += __shfl_xor(sq, off); }
  float mean = s * (1.0f / 768.0f);
  float rstd = rsqrtf(sq * (1.0f / 768.0f) - mean * mean + 1e-5f);
  ushort* o = out + row * 768;
#pragma unroll
  for (int i = 0; i < 3; ++i) {
    int base = i * 256 + l * 4;
    f32x4 gv = *(const f32x4*)(g + base);
    f32x4 bv = *(const f32x4*)(bta + base);
    u16x4 ov = { f2b((v[i*4+0] - mean) * rstd * gv[0] + bv[0]),
                 f2b((v[i*4+1] - mean) * rstd * gv[1] + bv[1]),
                 f2b((v[i*4+2] - mean) * rstd * gv[2] + bv[2]),
                 f2b((v[i*4+3] - mean) * rstd * gv[3] + bv[3]) };
    *(u16x4*)(o + base) = ov;
  }
}

// ---------------- patch extraction + LN1 (bf16 out), coalesced img loads ----------------
__global__ __launch_bounds__(256) void patch_ln1(const float* __restrict__ img,
                                                 const float* __restrict__ g,
                                                 const float* __restrict__ bta,
                                                 ushort* __restrict__ xp) {
  int pidx = blockIdx.x;                 // b*196 + ph*14 + pw
  int b = pidx / NPATCH, hw = pidx % NPATCH;
  int ph = hw / 14, pw = hw % 14;
  int t = threadIdx.x;
  int p1 = t >> 4, p2 = t & 15;
  float v[3];
#pragma unroll
  for (int c = 0; c < 3; ++c)
    v[c] = img[(((size_t)b * 3 + c) * 224 + ph * 16 + p1) * 224 + pw * 16 + p2];
  float mean, rstd;
  block_mean_rstd(v[0] + v[1] + v[2], v[0] * v[0] + v[1] * v[1] + v[2] * v[2], mean, rstd);
  ushort* o = xp + (size_t)pidx * 768;
#pragma unroll
  for (int c = 0; c < 3; ++c) {
    int k = t * 3 + c;
    o[k] = f2b((v[c] - mean) * rstd * g[k] + bta[k]);
  }
}

// ---------------- LN2 + pos_emb, scatter into x (bf16) at token 1+i ----------------
__global__ __launch_bounds__(256) void ln2_pos(const float* __restrict__ xe,
                                               const float* __restrict__ g,
                                               const float* __restrict__ bta,
                                               const float* __restrict__ pos,
                                               ushort* __restrict__ x) {
  int pidx = blockIdx.x;
  int b = pidx / NPATCH, i = pidx % NPATCH;
  const float* xr = xe + (size_t)pidx * 768;
  int t = threadIdx.x;
  float v0 = xr[t], v1 = xr[t + 256], v2 = xr[t + 512];
  float mean, rstd;
  block_mean_rstd(v0 + v1 + v2, v0 * v0 + v1 * v1 + v2 * v2, mean, rstd);
  const float* p = pos + (size_t)(1 + i) * 768;
  ushort* o = x + ((size_t)b * NTOK + 1 + i) * 768;
  o[t]       = f2b((v0 - mean) * rstd * g[t]       + bta[t]       + p[t]);
  o[t + 256] = f2b((v1 - mean) * rstd * g[t + 256] + bta[t + 256] + p[t + 256]);
  o[t + 512] = f2b((v2 - mean) * rstd * g[t + 512] + bta[t + 512] + p[t + 512]);
}

// ---------------- cls token + pos_emb[0] (bf16 out) ----------------
__global__ __launch_bounds__(256) void cls_init(const float* __restrict__ cls_tok,
                                                const float* __restrict__ pos,
                                                ushort* __restrict__ x) {
  int b = blockIdx.x, t = threadIdx.x;
  ushort* o = x + (size_t)b * NTOK * 768;
#pragma unroll
  for (int u = 0; u < 3; ++u) { int k = t + u * 256; o[k] = f2b(cls_tok[k] + pos[k]); }
}

// ---------------- cast + transpose: W fp32 [K][N] -> Wt bf16 [N][K] (bounds-checked) ----------------
__global__ __launch_bounds__(256) void transpose_cast(const float* __restrict__ W,
                                                      ushort* __restrict__ Wt,
                                                      int K, int N) {
  __shared__ float t[32][33];
  int n0 = blockIdx.x * 32, k0 = blockIdx.y * 32;
  int tx = threadIdx.x, ty = threadIdx.y;   // 32 x 8
#pragma unroll
  for (int u = 0; u < 32; u += 8) {
    int n = n0 + tx;
    t[ty + u][tx] = (n < N) ? W[(size_t)(k0 + ty + u) * N + n] : 0.f;
  }
  __syncthreads();
#pragma unroll
  for (int u = 0; u < 32; u += 8) {
    int n = n0 + ty + u;
    if (n < N) Wt[(size_t)n * K + k0 + tx] = f2b(t[tx][ty + u]);
  }
}

// ---------------- 128(K)x64(N) vectorized transpose v2, flat 256 thr ----------------
// f32x4 loads (256B segs), u16x4 writes of 128 contiguous k per n-row (256B segs).
// LDS float[128][64] flat with col' = col ^ ((k>>2)&31):
//   store: 16 lanes/row, stride-4 coset XOR const -> 2-way (free)
//   read:  lane kc reads rows 4kc..4kc+3 at bank (n^kc)&31 -> 32 distinct, conflict-free
__device__ __forceinline__ void transpose_layer128(int bid,
                                                   const float* wq, const float* wo,
                                                   const float* w1, const float* w2,
                                                   ushort* tq, ushort* to,
                                                   ushort* t1, ushort* t2) {
  const float* W; ushort* Wt; int K, N, xt;
  if (bid < 216)      {             W = wq; Wt = tq; K = 768;  N = 2304; xt = 36; }
  else if (bid < 288) { bid -= 216; W = wo; Wt = to; K = 768;  N = 768;  xt = 12; }
  else if (bid < 576) { bid -= 288; W = w1; Wt = t1; K = 768;  N = 3072; xt = 48; }
  else                { bid -= 576; W = w2; Wt = t2; K = 3072; N = 768;  xt = 12; }
  int n0 = (bid % xt) * 64, k0 = (bid / xt) * 128;
  __shared__ float t[128 * 64];
  int id = threadIdx.x;
#pragma unroll
  for (int pass = 0; pass < 8; ++pass) {
    int c = pass * 256 + id;
    int k = c >> 4, col = (c & 15) * 4;
    f32x4 v = *(const f32x4*)(W + (size_t)(k0 + k) * N + n0 + col);
    int s = (k >> 2) & 31;
#pragma unroll
    for (int j = 0; j < 4; ++j) t[k * 64 + ((col + j) ^ s)] = v[j];
  }
  __syncthreads();
#pragma unroll
  for (int pass = 0; pass < 8; ++pass) {
    int c = pass * 256 + id;
    int n = c >> 5, k = (c & 31) * 4;
    int s = (k >> 2) & 31;                 // same s for k..k+3
    u16x4 o = { f2b(t[(k + 0) * 64 + (n ^ s)]),
                f2b(t[(k + 1) * 64 + (n ^ s)]),
                f2b(t[(k + 2) * 64 + (n ^ s)]),
                f2b(t[(k + 3) * 64 + (n ^ s)]) };
    *(u16x4*)(Wt + (size_t)(n0 + n) * K + k0 + k) = o;
  }
}

__global__ __launch_bounds__(256) void transpose4(const float* __restrict__ wq,
                                                  const float* __restrict__ wo,
                                                  const float* __restrict__ w1,
                                                  const float* __restrict__ w2,
                                                  ushort* __restrict__ tq,
                                                  ushort* __restrict__ to,
                                                  ushort* __restrict__ t1,
                                                  ushort* __restrict__ t2) {
  transpose_layer128(blockIdx.x, wq, wo, w1, w2, tq, to, t1, t2);
}

__global__ __launch_bounds__(256) void transpose_all(const float* __restrict__ wq,
                                                     const float* __restrict__ wo,
                                                     const float* __restrict__ w1,
                                                     const float* __restrict__ w2,
                                                     ushort* __restrict__ tq,
                                                     ushort* __restrict__ to,
                                                     ushort* __restrict__ t1,
                                                     ushort* __restrict__ t2) {
  int l = blockIdx.x / 864, bid = blockIdx.x % 864;
  transpose_layer128(bid,
                     wq + (size_t)l * 768 * 2304, wo + (size_t)l * 768 * 768,
                     w1 + (size_t)l * 768 * MFF,  w2 + (size_t)l * MFF * 768,
                     tq + (size_t)l * 2304 * 768, to + (size_t)l * 768 * 768,
                     t1 + (size_t)l * MFF * 768,  t2 + (size_t)l * 768 * MFF);
}

// ================= bf16 MFMA GEMM v6: 2-buf counted-vmcnt (128x128) =================
template<int EP, int RESID, int OBF>
__global__ __launch_bounds__(256, 4) void gemm_v6(const ushort* __restrict__ A,
                                                  const ushort* __restrict__ Bt,
                                                  const float* __restrict__ bias,
                                                  const void* __restrict__ resid,
                                                  void* __restrict__ Cv,
                                                  int M, int N, int K) {
  __shared__ ushort smem[2 * 8192];

  const int tid = threadIdx.x;
  const int w = tid >> 6, l = tid & 63;
  const int fr = l & 15, fc = l >> 4;

  const int ntx = gridDim.x;
  const int nwg = ntx * gridDim.y;
  const int orig = blockIdx.y * ntx + blockIdx.x;
  const int q = nwg >> 3, r = nwg & 7, xcd = orig & 7, idx = orig >> 3;
  const int wg = (xcd < r ? xcd * (q + 1) : r * (q + 1) + (xcd - r) * q) + idx;
  const int row0 = (wg / ntx) * 128, col0 = (wg % ntx) * 128;

  const int wr = (w >> 1) * 64, wc = (w & 1) * 64;

  const int srow = tid >> 2;
  const int sg = (tid & 3) ^ ((srow >> 1) & 3);
  const ushort* pA0 = A  + (size_t)(row0 + srow) * K + sg * 8;
  const ushort* pA1 = A  + (size_t)(row0 + 64 + srow) * K + sg * 8;
  const ushort* pB0 = Bt + (size_t)(col0 + srow) * K + sg * 8;
  const ushort* pB1 = Bt + (size_t)(col0 + 64 + srow) * K + sg * 8;

  auto stage = [&](int t_, ushort* dst) {
    const int k0 = t_ * 32;
    gload16(pA0 + k0, dst + tid * 8);
    gload16(pA1 + k0, dst + (tid + 256) * 8);
    gload16(pB0 + k0, dst + 4096 + tid * 8);
    gload16(pB1 + k0, dst + 4096 + (tid + 256) * 8);
  };

  int idxA[4], idxB[4];
#pragma unroll
  for (int m = 0; m < 4; ++m) {
    int rA = wr + m * 16 + fr;
    idxA[m] = rA * 32 + ((fc ^ ((rA >> 1) & 3)) << 3);
  }
#pragma unroll
  for (int n = 0; n < 4; ++n) {
    int rB = wc + n * 16 + fr;
    idxB[n] = rB * 32 + ((fc ^ ((rB >> 1) & 3)) << 3);
  }

  f32x4 acc[4][4] = {};

  auto compute = [&](const ushort* As) {
    const ushort* Bs = As + 4096;
    bf16x8 a_[4], b_[4];
#pragma unroll
    for (int m = 0; m < 4; ++m) a_[m] = *(const bf16x8*)(As + idxA[m]);
#pragma unroll
    for (int n = 0; n < 4; ++n) b_[n] = *(const bf16x8*)(Bs + idxB[n]);
#pragma unroll
    for (int m = 0; m < 4; ++m)
#pragma unroll
      for (int n = 0; n < 4; ++n)
        acc[m][n] = __builtin_amdgcn_mfma_f32_16x16x32_bf16(b_[n], a_[m], acc[m][n], 0, 0, 0);
  };

#define VM4() asm volatile("s_waitcnt vmcnt(4)" ::: "memory")
#define VM0() asm volatile("s_waitcnt vmcnt(0)" ::: "memory")

  const int NT = K >> 5;

  stage(0, smem);
  for (int t = 0; t < NT; t += 2) {
    if (t + 1 < NT) { stage(t + 1, smem + 8192); VM4(); } else VM0();
    __builtin_amdgcn_s_barrier();
    compute(smem);
    __builtin_amdgcn_s_barrier();
    if (t + 1 < NT) {
      if (t + 2 < NT) { stage(t + 2, smem); VM4(); } else VM0();
      __builtin_amdgcn_s_barrier();
      compute(smem + 8192);
      __builtin_amdgcn_s_barrier();
    }
  }
#undef VM4
#undef VM0

  if (!OBF) {
    float* Cf = (float*)Cv;
#pragma unroll
    for (int m = 0; m < 4; ++m) {
      int row = row0 + wr + m * 16 + fr;
      if (row >= M) continue;
#pragma unroll
      for (int n = 0; n < 4; ++n) {
        int col = col0 + wc + n * 16 + fc * 4;
        f32x4 v = acc[m][n];
        if (bias) v += *(const f32x4*)(bias + col);
        if (EP) {
#pragma unroll
          for (int rr = 0; rr < 4; ++rr) v[rr] = gelu_f(v[rr]);
        }
        if (RESID) v += *(const f32x4*)((const float*)resid + (size_t)row * N + col);
        *(f32x4*)(Cf + (size_t)row * N + col) = v;
      }
    }
  } else {
    __syncthreads();
    ushort* Cw = smem + w * 4096;
#pragma unroll
    for (int m = 0; m < 4; ++m) {
      int rl = m * 16 + fr;
      int row = row0 + wr + rl;
#pragma unroll
      for (int n = 0; n < 4; ++n) {
        int col = col0 + wc + n * 16 + fc * 4;
        f32x4 v = acc[m][n];
        if (bias) v += *(const f32x4*)(bias + col);
        if (EP) {
#pragma unroll
          for (int rr = 0; rr < 4; ++rr) v[rr] = gelu_f(v[rr]);
        }
        if (RESID) {
          u16x4 rv = *(const u16x4*)((const ushort*)resid + (size_t)row * N + col);
#pragma unroll
          for (int rr = 0; rr < 4; ++rr) v[rr] += b2f(rv[rr]);
        }
        u16x4 pk = { f2b(v[0]), f2b(v[1]), f2b(v[2]), f2b(v[3]) };
        int s = (n * 4 + fc) ^ (rl & 7);
        *(u16x4*)(Cw + rl * 64 + s * 4) = pk;
      }
    }
    ushort* Cb = (ushort*)Cv;
#pragma unroll
    for (int pp = 0; pp < 16; ++pp) {
      int rl = pp * 4 + (l >> 4);
      int cs = l & 15;
      u16x4 pk = *(const u16x4*)(Cw + rl * 64 + ((cs ^ (rl & 7)) * 4));
      int row = row0 + wr + rl;
      if (row < M) *(u16x4*)(Cb + (size_t)row * N + col0 + wc + cs * 4) = pk;
    }
  }
}

// ---------------- 128x128 bf16 MFMA GEMM (head only, N-bounds-safe) ----------------
template<int EP, int RESID, int OBF>
__global__ __launch_bounds__(256) void gemm_bt(const ushort* __restrict__ A,
                                               const ushort* __restrict__ Bt,
                                               const float* __restrict__ bias,
                                               const float* __restrict__ resid,
                                               void* __restrict__ C,
                                               int M, int N, int K) {
  __shared__ ushort As[128 * 32];
  __shared__ ushort Bs[128 * 32];
  int tid = threadIdx.x;
  int w = tid >> 6, l = tid & 63;
  int fr = l & 15, fc = l >> 4;
  int row0 = blockIdx.y * 128, col0 = blockIdx.x * 128;
  int wr = (w >> 1) * 64, wc = (w & 1) * 64;

  int srow0 = w * 32 + (l >> 2);
  int srow1 = srow0 + 16;
  int sc0 = (((l & 3) ^ ((srow0 >> 1) & 3)) << 3);
  int sc1 = (((l & 3) ^ ((srow1 >> 1) & 3)) << 3);
  const ushort* ga0 = A  + (size_t)(row0 + srow0) * K + sc0;
  const ushort* ga1 = A  + (size_t)(row0 + srow1) * K + sc1;
  const ushort* gb0 = Bt + (size_t)(col0 + srow0) * K + sc0;
  const ushort* gb1 = Bt + (size_t)(col0 + srow1) * K + sc1;

  int idxA[4], idxB[4];
#pragma unroll
  for (int m = 0; m < 4; ++m) {
    int rA = wr + m * 16 + fr;
    idxA[m] = rA * 32 + ((fc ^ ((rA >> 1) & 3)) << 3);
  }
#pragma unroll
  for (int n = 0; n < 4; ++n) {
    int rB = wc + n * 16 + fr;
    idxB[n] = rB * 32 + ((fc ^ ((rB >> 1) & 3)) << 3);
  }

  f32x4 acc[4][4] = {};

  for (int k0 = 0; k0 < K; k0 += 32) {
    gload16(ga0 + k0, &As[w * 1024]);
    gload16(ga1 + k0, &As[w * 1024 + 512]);
    gload16(gb0 + k0, &Bs[w * 1024]);
    gload16(gb1 + k0, &Bs[w * 1024 + 512]);
    __syncthreads();
    bf16x8 af[4], bfr[4];
#pragma unroll
    for (int m = 0; m < 4; ++m) af[m] = *(const bf16x8*)(As + idxA[m]);
#pragma unroll
    for (int n = 0; n < 4; ++n) bfr[n] = *(const bf16x8*)(Bs + idxB[n]);
#pragma unroll
    for (int m = 0; m < 4; ++m)
#pragma unroll
      for (int n = 0; n < 4; ++n)
        acc[m][n] = __builtin_amdgcn_mfma_f32_16x16x32_bf16(af[m], bfr[n], acc[m][n], 0, 0, 0);
    __syncthreads();
  }

#pragma unroll
  for (int n = 0; n < 4; ++n) {
    int col = col0 + wc + n * 16 + fr;
    if (col >= N) continue;
    float bv = bias ? bias[col] : 0.f;
#pragma unroll
    for (int m = 0; m < 4; ++m) {
#pragma unroll
      for (int rr = 0; rr < 4; ++rr) {
        int row = row0 + wr + m * 16 + fc * 4 + rr;
        if (row >= M) continue;
        float v = acc[m][n][rr] + bv;
        if (EP == 1) v = 0.5f * v * (1.0f + erff(v * 0.70710678118654752f));
        if (RESID) v += resid[(size_t)row * N + col];
        if (OBF) ((ushort*)C)[(size_t)row * N + col] = f2b(v);
        else     ((float*)C)[(size_t)row * N + col]  = v;
      }
    }
  }
}

// ---------------- MFMA flash attention: K staged in LDS, (b,h)-per-XCD grid ----------------
__global__ __launch_bounds__(256) void attn_mfma(const ushort* __restrict__ qkv,
                                                 ushort* __restrict__ aout) {
  int bidp = blockIdx.x;
  int bh = (bidp & 7) | ((bidp >> 5) << 3);
  int qt = (bidp >> 3) & 3;
  int h  = bh % NH;
  int b  = bh / NH;
  int tid = threadIdx.x, w = tid >> 6, l = tid & 63;
  int fr = l & 15, fc = l >> 4;

  __shared__ ushort Kt[64 * 64];        // [key][64], slot'^=(key>>1)&7
  __shared__ ushort Vt[64 * 64];        // swizzled V^T tile [d][key]
  __shared__ ushort Pl[4 * 16 * 64];    // per-wave P [qrow][key], swizzled; reused for O

  const size_t brow = (size_t)b * NTOK;
  int q0 = qt * 64 + w * 16;

  const int skey = tid >> 3;
  const int sgk = (tid & 7) ^ ((skey >> 1) & 7);
  const ushort* pK0 = qkv + (brow + skey) * 2304 + 768 + h * 64 + sgk * 8;
  const ushort* pK1 = qkv + (brow + 32 + skey) * 2304 + 768 + h * 64 + sgk * 8;

  bf16x8 qf[2];
  {
    const ushort* qp = qkv + (brow + q0 + fr) * 2304 + h * 64 + fc * 8;
    qf[0] = *(const bf16x8*)qp;
    qf[1] = *(const bf16x8*)(qp + 32);
  }
  float rs[4] = {0.f, 0.f, 0.f, 0.f};
  f32x4 oc[4] = {};

  for (int kt = 0; kt < 4; ++kt) {
    __syncthreads();                      // prev tile's Kt/Vt reads complete
    {
      const size_t koff = (size_t)kt * 64 * 2304;
      gload16(pK0 + koff, Kt + tid * 8);
      gload16(pK1 + koff, Kt + (tid + 256) * 8);
    }
    {
      int key = tid >> 2, d0 = (tid & 3) * 16;
      int j = kt * 64 + key;
      bool valid = j < NTOK;
      const ushort* vp = qkv + (brow + j) * 2304 + 1536 + h * 64 + d0;
      ushort vbuf[16];
      if (valid) {
        *(bf16x8*)(vbuf)     = *(const bf16x8*)vp;
        *(bf16x8*)(vbuf + 8) = *(const bf16x8*)(vp + 8);
      } else {
#pragma unroll
        for (int i = 0; i < 16; ++i) vbuf[i] = 0;
      }
#pragma unroll
      for (int i = 0; i < 16; ++i) {
        int d = d0 + i;
        int byte = d * 128 + ((((key >> 3)) ^ (d & 7)) << 4) + (key & 7) * 2;
        Vt[byte >> 1] = vbuf[i];
      }
    }
    asm volatile("s_waitcnt vmcnt(0)" ::: "memory");   // K landed
    __syncthreads();                                   // Kt + Vt visible
    f32x4 sc[4];
#pragma unroll
    for (int n = 0; n < 4; ++n) {
      int row = n * 16 + fr;
      int sw = (row >> 1) & 7;
      const ushort* kr = Kt + row * 64;
      bf16x8 k0 = *(const bf16x8*)(kr + ((fc ^ sw) << 3));
      bf16x8 k1 = *(const bf16x8*)(kr + (((fc + 4) ^ sw) << 3));
      f32x4 z = {};
      z = __builtin_amdgcn_mfma_f32_16x16x32_bf16(qf[0], k0, z, 0, 0, 0);
      z = __builtin_amdgcn_mfma_f32_16x16x32_bf16(qf[1], k1, z, 0, 0, 0);
      sc[n] = z;
    }
    float part[4] = {0.f, 0.f, 0.f, 0.f};
#pragma unroll
    for (int n = 0; n < 4; ++n) {
      int j = kt * 64 + n * 16 + fr;
      bool jv = j < NTOK;
#pragma unroll
      for (int rr = 0; rr < 4; ++rr) {
        float e = jv ? __expf(sc[n][rr] * 0.125f) : 0.f;
        part[rr] += e;
        int row = fc * 4 + rr, col = n * 16 + fr;
        int byte = row * 128 + (((col >> 3) ^ (row & 7)) << 4) + (col & 7) * 2;
        Pl[w * 1024 + (byte >> 1)] = f2b(e);
      }
    }
#pragma unroll
    for (int rr = 0; rr < 4; ++rr) {
      float p = part[rr];
      p += __shfl_xor(p, 1); p += __shfl_xor(p, 2);
      p += __shfl_xor(p, 4); p += __shfl_xor(p, 8);
      rs[rr] += p;
    }
    __syncthreads();
#pragma unroll
    for (int ks = 0; ks < 2; ++ks) {
      int prow = fr;
      int pbyte = prow * 128 + (((ks * 4 + fc) ^ (prow & 7)) << 4);
      bf16x8 pf = *(const bf16x8*)(Pl + w * 1024 + (pbyte >> 1));
#pragma unroll
      for (int n = 0; n < 4; ++n) {
        int d = n * 16 + fr;
        int vb = d * 128 + (((ks * 4 + fc) ^ (d & 7)) << 4);
        bf16x8 vf = *(const bf16x8*)(Vt + (vb >> 1));
        oc[n] = __builtin_amdgcn_mfma_f32_16x16x32_bf16(pf, vf, oc[n], 0, 0, 0);
      }
    }
  }
  // epilogue: restage O through Pl (linear [16][64] per wave) -> u16x4 stores (128B rows)
  __syncthreads();                        // all PV reads of Pl done
  ushort* Ow = Pl + w * 1024;
#pragma unroll
  for (int n = 0; n < 4; ++n)
#pragma unroll
    for (int rr = 0; rr < 4; ++rr) {
      float v = oc[n][rr] / (rs[rr] + 1e-8f);
      Ow[(fc * 4 + rr) * 64 + n * 16 + fr] = f2b(v);
    }
  asm volatile("s_waitcnt lgkmcnt(0)" ::: "memory");
#pragma unroll
  for (int pass = 0; pass < 4; ++pass) {
    int rl = pass * 4 + (l >> 4);
    int d0 = (l & 15) * 4;
    u16x4 pk = *(const u16x4*)(Ow + rl * 64 + d0);
    int qq = q0 + rl;
    if (qq < NTOK)
      *(u16x4*)(aout + (brow + qq) * 768 + h * 64 + d0) = pk;
  }
}

// ---------------- host launch ----------------
extern "C" void kernel_launch(void* const* d_in, const int* in_sizes, int n_in,
                              void* d_out, int out_size, void* d_ws, size_t ws_size,
                              hipStream_t stream) {
  const float* img       = (const float*)d_in[0];
  const float* p_ln1_g   = (const float*)d_in[1];
  const float* p_ln1_b   = (const float*)d_in[2];
  const float* patch_w   = (const float*)d_in[3];
  const float* patch_b   = (const float*)d_in[4];
  const float* p_ln2_g   = (const float*)d_in[5];
  const float* p_ln2_b   = (const float*)d_in[6];
  const float* pos_emb   = (const float*)d_in[7];
  const float* cls_tok   = (const float*)d_in[8];
  const float* attn_ln_g = (const float*)d_in[9];
  const float* attn_ln_b = (const float*)d_in[10];
  const float* w_qkv     = (const float*)d_in[11];
  const float* w_out     = (const float*)d_in[12];
  const float* b_out     = (const float*)d_in[13];
  const float* ff_ln_g   = (const float*)d_in[14];
  const float* ff_ln_b   = (const float*)d_in[15];
  const float* ff_w1     = (const float*)d_in[16];
  const float* ff_b1     = (const float*)d_in[17];
  const float* ff_w2     = (const float*)d_in[18];
  const float* ff_b2     = (const float*)d_in[19];
  const float* fin_ln_g  = (const float*)d_in[20];
  const float* fin_ln_b  = (const float*)d_in[21];
  const float* head_w    = (const float*)d_in[22];
  const float* head_b    = (const float*)d_in[23];
  float* out = (float*)d_out;

  // ---- workspace carve ----
  char* p = (char*)d_ws;
  auto alloc = [&](size_t bytes) { char* r = p; p += (bytes + 255) & ~(size_t)255; return r; };
  ushort* x      = (ushort*)alloc((size_t)ROWS_PAD * 768 * 2);    // bf16 residual stream
  ushort* xnb    = (ushort*)alloc((size_t)ROWS_PAD * 768 * 2);
  ushort* qkvb   = (ushort*)alloc((size_t)ROWS_PAD * 2304 * 2);
  ushort* aoutb  = (ushort*)alloc((size_t)ROWS_PAD * 768 * 2);
  ushort* pwt    = (ushort*)alloc((size_t)768 * 768 * 2);
  ushort* hwt    = (ushort*)alloc((size_t)1024 * 768 * 2);
  ushort* xclsb  = (ushort*)alloc((size_t)128 * 768 * 2);
  ushort* hidb   = qkvb;                 // [ROWS_PAD][3072] aliases qkvb+aoutb
  ushort* xpb    = xnb;                  // patch LN1 out (12544 rows)
  float*  xe     = (float*)qkvb;         // patch GEMM out fp32 (pre-loop only)

  const size_t SQ = (size_t)2304 * 768, SO = (size_t)768 * 768, S1 = (size_t)MFF * 768;
  size_t used = (size_t)(p - (char*)d_ws);
  bool oneshot = (used + 12 * (SQ + SO + 2 * S1) * 2 + 4096) <= ws_size;
  int nw = oneshot ? 12 : 1;
  ushort* wtq = (ushort*)alloc(nw * SQ * 2);
  ushort* wto = (ushort*)alloc(nw * SO * 2);
  ushort* wt1 = (ushort*)alloc(nw * S1 * 2);
  ushort* wt2 = (ushort*)alloc(nw * S1 * 2);

  dim3 blk(256), tblk(32, 8);

  // ---- patch embedding ----
  transpose_cast<<<dim3(24, 24), tblk, 0, stream>>>(patch_w, pwt, 768, 768);
  transpose_cast<<<dim3(32, 24), tblk, 0, stream>>>(head_w, hwt, 768, 1000);
  if (oneshot)
    transpose_all<<<12 * 864, blk, 0, stream>>>(w_qkv, w_out, ff_w1, ff_w2,
                                                wtq, wto, wt1, wt2);
  patch_ln1<<<PROWS, blk, 0, stream>>>(img, p_ln1_g, p_ln1_b, xpb);
  gemm_v6<0, 0, 0><<<dim3(6, 98), blk, 0, stream>>>(xpb, pwt, patch_b, nullptr, xe,
                                                    PROWS, 768, 768);
  ln2_pos<<<PROWS, blk, 0, stream>>>(xe, p_ln2_g, p_ln2_b, pos_emb, x);
  cls_init<<<B_, blk, 0, stream>>>(cls_tok, pos_emb, x);

  for (int l = 0; l < NL; ++l) {
    ushort* tq = wtq + (oneshot ? (size_t)l * SQ : 0);
    ushort* to = wto + (oneshot ? (size_t)l * SO : 0);
    ushort* t1 = wt1 + (oneshot ? (size_t)l * S1 : 0);
    ushort* t2 = wt2 + (oneshot ? (size_t)l * S1 : 0);
    if (!oneshot)
      transpose4<<<864, blk, 0, stream>>>(w_qkv + (size_t)l * 768 * 2304,
                                          w_out + (size_t)l * 768 * 768,
                                          ff_w1 + (size_t)l * 768 * MFF,
                                          ff_w2 + (size_t)l * MFF * 768,
                                          tq, to, t1, t2);

    ln_rows4<<<ROWS / 4, blk, 0, stream>>>(x, 768, attn_ln_g + (size_t)l * 768,
                                           attn_ln_b + (size_t)l * 768, xnb);
    gemm_v6<0, 0, 1><<<dim3(18, 99), blk, 0, stream>>>(xnb, tq, nullptr, nullptr, qkvb,
                                                       ROWS, 2304, 768);
    attn_mfma<<<B_ * NH * 4, blk, 0, stream>>>(qkvb, aoutb);
    gemm_v6<0, 1, 1><<<dim3(6, 99), blk, 0, stream>>>(aoutb, to, b_out + (size_t)l * 768,
                                                      x, x, ROWS, 768, 768);
    ln_rows4<<<ROWS / 4, blk, 0, stream>>>(x, 768, ff_ln_g + (size_t)l * 768,
                                           ff_ln_b + (size_t)l * 768, xnb);
    gemm_v6<1, 0, 1><<<dim3(24, 99), blk, 0, stream>>>(xnb, t1, ff_b1 + (size_t)l * MFF,
                                                       nullptr, hidb, ROWS, MFF, 768);
    gemm_v6<0, 1, 1><<<dim3(6, 99), blk, 0, stream>>>(hidb, t2, ff_b2 + (size_t)l * 768,
                                                      x, x, ROWS, 768, MFF);
  }

  // ---- final LN (cls rows) + head ----
  ln_rows4<<<B_ / 4, blk, 0, stream>>>(x, (long)NTOK * 768, fin_ln_g, fin_ln_b, xclsb);
  gemm_bt<0, 0, 0><<<dim3(8, 1), blk, 0, stream>>>(xclsb, hwt, head_b, nullptr, out,
                                                   B_, NCLS, 768);
}